// Round 1
// baseline (731.277 us; speedup 1.0000x reference)
//
#include <hip/hip_runtime.h>

__device__ __forceinline__ float warpsum(float v) {
    for (int off = 32; off > 0; off >>= 1) v += __shfl_down(v, off);
    return v;
}

// ---------------- K0: pooled mean of x1 channels ----------------
__global__ __launch_bounds__(256) void k_pool(const float* __restrict__ x, float* __restrict__ pooled1) {
    int bid = blockIdx.x;            // 64 = b*16 + c
    int b = bid >> 4, c = bid & 15;
    const float* base = x + (size_t)(b * 64 + c) * 65536;
    float s = 0.f;
    for (int i = threadIdx.x; i < 16384; i += 256) {
        float4 v = ((const float4*)base)[i];
        s += v.x + v.y + v.z + v.w;
    }
    __shared__ float red[4];
    s = warpsum(s);
    if ((threadIdx.x & 63) == 0) red[threadIdx.x >> 6] = s;
    __syncthreads();
    if (threadIdx.x == 0) pooled1[bid] = (red[0] + red[1] + red[2] + red[3]) * (1.f / 65536.f);
}

// ---------------- K1: kern1 from pooled1 (tiny MLP) ----------------
__global__ __launch_bounds__(256) void k_kern1(const float* __restrict__ pooled1,
                                               const float* __restrict__ w1, const float* __restrict__ b1,
                                               const float* __restrict__ w2, const float* __restrict__ b2,
                                               float* __restrict__ kern1) {
    __shared__ float h[64];
    int t = threadIdx.x;
    if (t < 64) {
        int b = t >> 4, j = t & 15;
        float a = b1[j];
        for (int i = 0; i < 16; ++i) a += pooled1[b * 16 + i] * w1[j * 16 + i];
        h[t] = fmaxf(a, 0.f);
    }
    __syncthreads();
    for (int i = t; i < 576; i += 256) {      // 4 * 144
        int b = i / 144, o = i - b * 144;
        float a = b2[o];
        for (int j = 0; j < 16; ++j) a += h[b * 16 + j] * w2[o * 16 + j];
        kern1[i] = a;
    }
}

// ---------------- K2: dynamic depthwise 3x3 + per-row sums ----------------
__global__ __launch_bounds__(256) void k_dw3(const float* __restrict__ x,
                                             const float* __restrict__ kern1,
                                             float* __restrict__ y1, float* __restrict__ rowsum) {
    int bid = blockIdx.x;            // (b*16+c)*256 + row
    int row = bid & 255;
    int bc = bid >> 8;
    int b = bc >> 4, c = bc & 15;
    int col = threadIdx.x;
    const float* k9 = kern1 + b * 144 + c * 9;
    float kk[9];
#pragma unroll
    for (int i = 0; i < 9; ++i) kk[i] = k9[i];
    const float* xc = x + (size_t)(b * 64 + c) * 65536;
    float acc = 0.f;
#pragma unroll
    for (int dy = 0; dy < 3; ++dy) {
        int r = row + dy - 1;
        if ((unsigned)r < 256u) {
            const float* xr = xc + r * 256;
#pragma unroll
            for (int dx = 0; dx < 3; ++dx) {
                int cc = col + dx - 1;
                float v = ((unsigned)cc < 256u) ? xr[cc] : 0.f;
                acc += kk[dy * 3 + dx] * v;
            }
        }
    }
    y1[(size_t)bc * 65536 + row * 256 + col] = acc;
    float s = warpsum(acc);
    __shared__ float red[4];
    if ((threadIdx.x & 63) == 0) red[threadIdx.x >> 6] = s;
    __syncthreads();
    if (threadIdx.x == 0) rowsum[bid] = red[0] + red[1] + red[2] + red[3];
}

// ---------------- K3: kern2 from row sums (tiny MLP) ----------------
__global__ __launch_bounds__(256) void k_kern2(const float* __restrict__ rowsum,
                                               const float* __restrict__ w1, const float* __restrict__ b1,
                                               const float* __restrict__ w2, const float* __restrict__ b2,
                                               float* __restrict__ kern2) {
    __shared__ float ps[256];
    __shared__ float p2[64];
    __shared__ float h[64];
    int t = threadIdx.x;
    {
        int pair = t >> 2, seg = t & 3;
        const float* rs = rowsum + pair * 256 + seg * 64;
        float s = 0.f;
        for (int j = 0; j < 64; ++j) s += rs[j];
        ps[t] = s;
    }
    __syncthreads();
    if (t < 64) p2[t] = (ps[t * 4] + ps[t * 4 + 1] + ps[t * 4 + 2] + ps[t * 4 + 3]) * (1.f / 65536.f);
    __syncthreads();
    if (t < 64) {
        int b = t >> 4, j = t & 15;
        float a = b1[j];
        for (int i = 0; i < 16; ++i) a += p2[b * 16 + i] * w1[j * 16 + i];
        h[t] = fmaxf(a, 0.f);
    }
    __syncthreads();
    for (int i = t; i < 1600; i += 256) {     // 4 * 400
        int b = i / 400, o = i - b * 400;
        float a = b2[o];
        for (int j = 0; j < 16; ++j) a += h[b * 16 + j] * w2[o * 16 + j];
        kern2[i] = a;
    }
}

// ---------------- K4: dynamic depthwise 5x5 ----------------
__global__ __launch_bounds__(256) void k_dw5(const float* __restrict__ y1,
                                             const float* __restrict__ kern2,
                                             float* __restrict__ x1o) {
    int bid = blockIdx.x;
    int row = bid & 255;
    int bc = bid >> 8;
    int b = bc >> 4, c = bc & 15;
    int col = threadIdx.x;
    const float* k25 = kern2 + b * 400 + c * 25;
    float kk[25];
#pragma unroll
    for (int i = 0; i < 25; ++i) kk[i] = k25[i];
    const float* yc = y1 + (size_t)bc * 65536;
    float acc = 0.f;
#pragma unroll
    for (int dy = 0; dy < 5; ++dy) {
        int r = row + dy - 2;
        if ((unsigned)r < 256u) {
            const float* yr = yc + r * 256;
#pragma unroll
            for (int dx = 0; dx < 5; ++dx) {
                int cc = col + dx - 2;
                float v = ((unsigned)cc < 256u) ? yr[cc] : 0.f;
                acc += kk[dy * 5 + dx] * v;
            }
        }
    }
    x1o[(size_t)bc * 65536 + row * 256 + col] = acc;
}

// ---------------- K5: fused fsas + final conv, one 8x8 patch per block ----------------
// LDS (62592 B): reg0 = x2t[48][100] -> outb[48][64] -> lw[64][64]
//                reg1 = hid24[24][100] -> ow[48][48]
//                qbuf = q[48][64] -> sbuf ; kbuf = k[48][64] -> x2o
__global__ __launch_bounds__(512) void k_fsas(const float* __restrict__ x,
                                              const float* __restrict__ hid_w, const float* __restrict__ hid_b,
                                              const float* __restrict__ dw_w, const float* __restrict__ dw_b,
                                              const float* __restrict__ ln_w, const float* __restrict__ ln_b,
                                              const float* __restrict__ out_w, const float* __restrict__ out_b,
                                              const float* __restrict__ last_w, const float* __restrict__ last_b,
                                              const float* __restrict__ x1o, float* __restrict__ out) {
    __shared__ __align__(16) float reg0[4800];
    __shared__ __align__(16) float reg1[2400];
    __shared__ __align__(16) float qbuf[3072];
    __shared__ __align__(16) float kbuf[3072];
    __shared__ __align__(16) float x1t[1024];
    __shared__ __align__(16) float wslice[1152];
    __shared__ float pstat[128];

    int tid = threadIdx.x;
    int wave = tid >> 6, lane = tid & 63;
    int bid = blockIdx.x;
    int b = bid >> 10;
    int rem = bid & 1023;
    int ph = rem >> 5, pw = rem & 31;
    int row0 = ph << 3, col0 = pw << 3;

    // ---- stage 1: load x2 halo tile (zero-padded) + x1_out tile ----
    for (int i = tid; i < 4800; i += 512) {
        int c = i / 100, p = i - c * 100;
        int y = p / 10, xx = p - y * 10;
        int gy = row0 - 1 + y, gx = col0 - 1 + xx;
        float v = 0.f;
        if ((unsigned)gy < 256u && (unsigned)gx < 256u)
            v = x[((size_t)(b * 64 + 16 + c) << 16) + (gy << 8) + gx];
        reg0[i] = v;
    }
    for (int k = tid; k < 1024; k += 512) {
        int c = k >> 6, pix = k & 63;
        x1t[k] = x1o[((size_t)(b * 16 + c) << 16) + ((row0 + (pix >> 3)) << 8) + col0 + (pix & 7)];
    }
    __syncthreads();

    // ---- stage 2: hidden conv1x1 (48->144) + depthwise 3x3, phases q/k/v ----
    float vreg[6];
#pragma unroll 1
    for (int phase = 0; phase < 3; ++phase) {
        float* dst = (phase == 0) ? qbuf : kbuf;
#pragma unroll 1
        for (int sub = 0; sub < 2; ++sub) {
            int cbase = phase * 48 + sub * 24;
            for (int i = tid; i < 1152; i += 512) wslice[i] = hid_w[cbase * 48 + i];
            __syncthreads();
            {
                int cl0 = wave * 3;
                float bb0 = hid_b[cbase + cl0];
                float bb1 = hid_b[cbase + cl0 + 1];
                float bb2 = hid_b[cbase + cl0 + 2];
                const float* w0 = wslice + cl0 * 48;
#pragma unroll 1
                for (int half = 0; half < 2; ++half) {
                    int p = (half << 6) + lane;
                    int pp = (p < 100) ? p : 0;
                    float a0 = bb0, a1 = bb1, a2 = bb2;
#pragma unroll
                    for (int ci = 0; ci < 48; ci += 4) {
                        float4 wa = *(const float4*)(w0 + ci);
                        float4 wb = *(const float4*)(w0 + 48 + ci);
                        float4 wc = *(const float4*)(w0 + 96 + ci);
                        float x0 = reg0[(ci)     * 100 + pp];
                        float x1 = reg0[(ci + 1) * 100 + pp];
                        float x2 = reg0[(ci + 2) * 100 + pp];
                        float x3 = reg0[(ci + 3) * 100 + pp];
                        a0 += wa.x * x0 + wa.y * x1 + wa.z * x2 + wa.w * x3;
                        a1 += wb.x * x0 + wb.y * x1 + wb.z * x2 + wb.w * x3;
                        a2 += wc.x * x0 + wc.y * x1 + wc.z * x2 + wc.w * x3;
                    }
                    if (p < 100) {
                        int y = pp / 10, xx = pp - y * 10;
                        int gy = row0 - 1 + y, gx = col0 - 1 + xx;
                        bool inb = ((unsigned)gy < 256u) && ((unsigned)gx < 256u);
                        reg1[(cl0)     * 100 + p] = inb ? a0 : 0.f;
                        reg1[(cl0 + 1) * 100 + p] = inb ? a1 : 0.f;
                        reg1[(cl0 + 2) * 100 + p] = inb ? a2 : 0.f;
                    }
                }
            }
            __syncthreads();
#pragma unroll
            for (int it = 0; it < 3; ++it) {
                int i = tid + (it << 9);
                int cl = i >> 6, pix = i & 63;
                int c = cbase + cl;
                int y = pix >> 3, xx = pix & 7;
                const float* dwp = dw_w + c * 9;
                float acc = dw_b[c];
#pragma unroll
                for (int dy = 0; dy < 3; ++dy)
#pragma unroll
                    for (int dx = 0; dx < 3; ++dx)
                        acc += dwp[dy * 3 + dx] * reg1[cl * 100 + (y + dy) * 10 + (xx + dx)];
                if (phase < 2) dst[(sub * 24 + cl) * 64 + pix] = acc;
                else vreg[sub * 3 + it] = acc;
            }
            __syncthreads();
        }
    }

    // ---- stage 3: 8x8 circular convolution out = q (*) k (register-tiled, 1 row/lane) ----
    float co[8];
    int cc_c = tid >> 3, cc_m = tid & 7;
    if (tid < 384) {
        const float* qr = qbuf + cc_c * 64;
        const float* kr = kbuf + cc_c * 64;
#pragma unroll
        for (int n = 0; n < 8; ++n) co[n] = 0.f;
#pragma unroll
        for (int i8 = 0; i8 < 8; ++i8) {
            int r = (cc_m - i8) & 7;
            float4 ka = *(const float4*)(kr + r * 8);
            float4 kb4 = *(const float4*)(kr + r * 8 + 4);
            float kg[8] = {ka.x, ka.y, ka.z, ka.w, kb4.x, kb4.y, kb4.z, kb4.w};
            float4 qa = *(const float4*)(qr + i8 * 8);
            float4 qb4 = *(const float4*)(qr + i8 * 8 + 4);
            float qg[8] = {qa.x, qa.y, qa.z, qa.w, qb4.x, qb4.y, qb4.z, qb4.w};
#pragma unroll
            for (int j = 0; j < 8; ++j)
#pragma unroll
                for (int n = 0; n < 8; ++n)
                    co[n] += qg[j] * kg[(n - j) & 7];
        }
    }
    __syncthreads();                 // all q/k reads done
    if (tid < 384) {
#pragma unroll
        for (int n = 0; n < 8; ++n) reg0[cc_c * 64 + cc_m * 8 + n] = co[n];  // outb
    }
    __syncthreads();

    // ---- stage 4a: layernorm stats per pixel over 48 channels ----
    if (tid < 64) {
        float s = 0.f, ss = 0.f;
#pragma unroll
        for (int c = 0; c < 48; ++c) {
            float v = reg0[c * 64 + tid];
            s += v; ss += v * v;
        }
        float mu = s * (1.f / 48.f);
        float var = ss * (1.f / 48.f) - mu * mu;
        pstat[tid * 2] = mu;
        pstat[tid * 2 + 1] = rsqrtf(var + 1e-6f);
    }
    for (int i = tid; i < 2304; i += 512) reg1[i] = out_w[i];  // stage out_w
    __syncthreads();

    // ---- stage 4b: sbuf = v * layernorm(out) ----
    {
        int pix = tid & 63;
        float mu = pstat[pix * 2], inv = pstat[pix * 2 + 1];
#pragma unroll
        for (int k = 0; k < 6; ++k) {
            int sub = k / 3, it = k - sub * 3;
            int c = sub * 24 + (tid >> 6) + (it << 3);
            float o = reg0[c * 64 + pix];
            float lnv = ln_w[c] * ((o - mu) * inv) + ln_b[c];
            qbuf[c * 64 + pix] = vreg[k] * lnv;    // sbuf
        }
    }
    __syncthreads();

    // ---- stage 5: x2o = out_w @ sbuf + out_b ; stage last_w ----
    {
        int o0 = wave * 6;
        float acc[6];
#pragma unroll
        for (int u = 0; u < 6; ++u) acc[u] = out_b[o0 + u];
#pragma unroll
        for (int ci = 0; ci < 48; ci += 4) {
            float s0 = qbuf[(ci)     * 64 + lane];
            float s1 = qbuf[(ci + 1) * 64 + lane];
            float s2 = qbuf[(ci + 2) * 64 + lane];
            float s3 = qbuf[(ci + 3) * 64 + lane];
#pragma unroll
            for (int u = 0; u < 6; ++u) {
                float4 w4 = *(const float4*)(reg1 + (o0 + u) * 48 + ci);
                acc[u] += w4.x * s0 + w4.y * s1 + w4.z * s2 + w4.w * s3;
            }
        }
#pragma unroll
        for (int u = 0; u < 6; ++u) kbuf[(o0 + u) * 64 + lane] = acc[u];  // x2o
    }
    for (int i = tid; i < 4096; i += 512) reg0[i] = last_w[i];  // lw
    __syncthreads();

    // ---- stage 6: final conv1x1 (64->64) over [x1_out ; x2o] ----
    {
        int pix = tid & 63;
#pragma unroll 1
        for (int it = 0; it < 8; ++it) {
            int o = (tid >> 6) + (it << 3);
            const float* lwr = reg0 + o * 64;
            float acc = last_b[o];
#pragma unroll
            for (int ci = 0; ci < 16; ci += 4) {
                float4 w4 = *(const float4*)(lwr + ci);
                acc += w4.x * x1t[(ci)     * 64 + pix] + w4.y * x1t[(ci + 1) * 64 + pix]
                     + w4.z * x1t[(ci + 2) * 64 + pix] + w4.w * x1t[(ci + 3) * 64 + pix];
            }
#pragma unroll
            for (int ci = 0; ci < 48; ci += 4) {
                float4 w4 = *(const float4*)(lwr + 16 + ci);
                acc += w4.x * kbuf[(ci)     * 64 + pix] + w4.y * kbuf[(ci + 1) * 64 + pix]
                     + w4.z * kbuf[(ci + 2) * 64 + pix] + w4.w * kbuf[(ci + 3) * 64 + pix];
            }
            out[((size_t)(b * 64 + o) << 16) + ((row0 + (pix >> 3)) << 8) + col0 + (pix & 7)] = acc;
        }
    }
}

extern "C" void kernel_launch(void* const* d_in, const int* in_sizes, int n_in,
                              void* d_out, int out_size, void* d_ws, size_t ws_size,
                              hipStream_t stream) {
    const float* x      = (const float*)d_in[0];
    const float* dl1_w1 = (const float*)d_in[1];
    const float* dl1_b1 = (const float*)d_in[2];
    const float* dl1_w2 = (const float*)d_in[3];
    const float* dl1_b2 = (const float*)d_in[4];
    const float* dl2_w1 = (const float*)d_in[5];
    const float* dl2_b1 = (const float*)d_in[6];
    const float* dl2_w2 = (const float*)d_in[7];
    const float* dl2_b2 = (const float*)d_in[8];
    const float* hid_w  = (const float*)d_in[9];
    const float* hid_b  = (const float*)d_in[10];
    const float* dw_w   = (const float*)d_in[11];
    const float* dw_b   = (const float*)d_in[12];
    const float* ln_w   = (const float*)d_in[13];
    const float* ln_b   = (const float*)d_in[14];
    const float* out_w  = (const float*)d_in[15];
    const float* out_b  = (const float*)d_in[16];
    const float* last_w = (const float*)d_in[17];
    const float* last_b = (const float*)d_in[18];
    float* out = (float*)d_out;

    float* ws      = (float*)d_ws;
    float* pooled1 = ws;                       // 64
    float* kern1   = ws + 64;                  // 576
    float* rowsum  = ws + 1024;                // 16384
    float* kern2   = ws + 17408;               // 1600
    float* y1      = ws + 32768;               // 4194304
    float* x1o     = ws + 32768 + 4194304;     // 4194304

    k_pool <<<64,    256, 0, stream>>>(x, pooled1);
    k_kern1<<<1,     256, 0, stream>>>(pooled1, dl1_w1, dl1_b1, dl1_w2, dl1_b2, kern1);
    k_dw3  <<<16384, 256, 0, stream>>>(x, kern1, y1, rowsum);
    k_kern2<<<1,     256, 0, stream>>>(rowsum, dl2_w1, dl2_b1, dl2_w2, dl2_b2, kern2);
    k_dw5  <<<16384, 256, 0, stream>>>(y1, kern2, x1o);
    k_fsas <<<4096,  512, 0, stream>>>(x, hid_w, hid_b, dw_w, dw_b, ln_w, ln_b,
                                       out_w, out_b, last_w, last_b, x1o, out);
}

// Round 2
// 402.791 us; speedup vs baseline: 1.8155x; 1.8155x over previous
//
#include <hip/hip_runtime.h>

__device__ __forceinline__ float warpsum(float v) {
    for (int off = 32; off > 0; off >>= 1) v += __shfl_down(v, off);
    return v;
}

// ---------------- K_prep: transpose weights for SGPR-friendly access ----------------
__global__ __launch_bounds__(256) void k_prep(const float* __restrict__ hid_w,
                                              const float* __restrict__ out_w,
                                              const float* __restrict__ last_w,
                                              float* __restrict__ hwT,
                                              float* __restrict__ owT,
                                              float* __restrict__ lwT) {
    int t = blockIdx.x * 256 + threadIdx.x;
    int stride = gridDim.x * 256;
    for (int i = t; i < 6912; i += stride) {          // hwT[ci][o] = hid_w[o][ci], 48x144
        int ci = i / 144, o = i - ci * 144;
        hwT[i] = hid_w[o * 48 + ci];
    }
    for (int i = t; i < 2304; i += stride) {          // owT[ci][o] = out_w[o][ci], 48x48
        int ci = i / 48, o = i - ci * 48;
        owT[i] = out_w[o * 48 + ci];
    }
    for (int i = t; i < 4096; i += stride) {          // lwT[ci][o] = last_w[o][ci], 64x64
        int ci = i >> 6, o = i & 63;
        lwT[i] = last_w[o * 64 + ci];
    }
}

// ---------------- K0: pooled mean of x1 channels ----------------
__global__ __launch_bounds__(256) void k_pool(const float* __restrict__ x, float* __restrict__ pooled1) {
    int bid = blockIdx.x;            // 64 = b*16 + c
    int b = bid >> 4, c = bid & 15;
    const float* base = x + (size_t)(b * 64 + c) * 65536;
    float s = 0.f;
    for (int i = threadIdx.x; i < 16384; i += 256) {
        float4 v = ((const float4*)base)[i];
        s += v.x + v.y + v.z + v.w;
    }
    __shared__ float red[4];
    s = warpsum(s);
    if ((threadIdx.x & 63) == 0) red[threadIdx.x >> 6] = s;
    __syncthreads();
    if (threadIdx.x == 0) pooled1[bid] = (red[0] + red[1] + red[2] + red[3]) * (1.f / 65536.f);
}

// ---------------- K1: kern1 from pooled1 (tiny MLP) ----------------
__global__ __launch_bounds__(256) void k_kern1(const float* __restrict__ pooled1,
                                               const float* __restrict__ w1, const float* __restrict__ b1,
                                               const float* __restrict__ w2, const float* __restrict__ b2,
                                               float* __restrict__ kern1) {
    __shared__ float h[64];
    int t = threadIdx.x;
    if (t < 64) {
        int b = t >> 4, j = t & 15;
        float a = b1[j];
        for (int i = 0; i < 16; ++i) a += pooled1[b * 16 + i] * w1[j * 16 + i];
        h[t] = fmaxf(a, 0.f);
    }
    __syncthreads();
    for (int i = t; i < 576; i += 256) {      // 4 * 144
        int b = i / 144, o = i - b * 144;
        float a = b2[o];
        for (int j = 0; j < 16; ++j) a += h[b * 16 + j] * w2[o * 16 + j];
        kern1[i] = a;
    }
}

// ---------------- K2: dynamic depthwise 3x3 + per-row sums ----------------
__global__ __launch_bounds__(256) void k_dw3(const float* __restrict__ x,
                                             const float* __restrict__ kern1,
                                             float* __restrict__ y1, float* __restrict__ rowsum) {
    int bid = blockIdx.x;            // (b*16+c)*256 + row
    int row = bid & 255;
    int bc = bid >> 8;
    int b = bc >> 4, c = bc & 15;
    int col = threadIdx.x;
    const float* k9 = kern1 + b * 144 + c * 9;
    float kk[9];
#pragma unroll
    for (int i = 0; i < 9; ++i) kk[i] = k9[i];
    const float* xc = x + (size_t)(b * 64 + c) * 65536;
    float acc = 0.f;
#pragma unroll
    for (int dy = 0; dy < 3; ++dy) {
        int r = row + dy - 1;
        if ((unsigned)r < 256u) {
            const float* xr = xc + r * 256;
#pragma unroll
            for (int dx = 0; dx < 3; ++dx) {
                int cc = col + dx - 1;
                float v = ((unsigned)cc < 256u) ? xr[cc] : 0.f;
                acc += kk[dy * 3 + dx] * v;
            }
        }
    }
    y1[(size_t)bc * 65536 + row * 256 + col] = acc;
    float s = warpsum(acc);
    __shared__ float red[4];
    if ((threadIdx.x & 63) == 0) red[threadIdx.x >> 6] = s;
    __syncthreads();
    if (threadIdx.x == 0) rowsum[bid] = red[0] + red[1] + red[2] + red[3];
}

// ---------------- K3: kern2 from row sums (tiny MLP) ----------------
__global__ __launch_bounds__(256) void k_kern2(const float* __restrict__ rowsum,
                                               const float* __restrict__ w1, const float* __restrict__ b1,
                                               const float* __restrict__ w2, const float* __restrict__ b2,
                                               float* __restrict__ kern2) {
    __shared__ float ps[256];
    __shared__ float p2[64];
    __shared__ float h[64];
    int t = threadIdx.x;
    {
        int pair = t >> 2, seg = t & 3;
        const float* rs = rowsum + pair * 256 + seg * 64;
        float s = 0.f;
        for (int j = 0; j < 64; ++j) s += rs[j];
        ps[t] = s;
    }
    __syncthreads();
    if (t < 64) p2[t] = (ps[t * 4] + ps[t * 4 + 1] + ps[t * 4 + 2] + ps[t * 4 + 3]) * (1.f / 65536.f);
    __syncthreads();
    if (t < 64) {
        int b = t >> 4, j = t & 15;
        float a = b1[j];
        for (int i = 0; i < 16; ++i) a += p2[b * 16 + i] * w1[j * 16 + i];
        h[t] = fmaxf(a, 0.f);
    }
    __syncthreads();
    for (int i = t; i < 1600; i += 256) {     // 4 * 400
        int b = i / 400, o = i - b * 400;
        float a = b2[o];
        for (int j = 0; j < 16; ++j) a += h[b * 16 + j] * w2[o * 16 + j];
        kern2[i] = a;
    }
}

// ---------------- K4: dynamic depthwise 5x5 ----------------
__global__ __launch_bounds__(256) void k_dw5(const float* __restrict__ y1,
                                             const float* __restrict__ kern2,
                                             float* __restrict__ x1o) {
    int bid = blockIdx.x;
    int row = bid & 255;
    int bc = bid >> 8;
    int b = bc >> 4, c = bc & 15;
    int col = threadIdx.x;
    const float* k25 = kern2 + b * 400 + c * 25;
    float kk[25];
#pragma unroll
    for (int i = 0; i < 25; ++i) kk[i] = k25[i];
    const float* yc = y1 + (size_t)bc * 65536;
    float acc = 0.f;
#pragma unroll
    for (int dy = 0; dy < 5; ++dy) {
        int r = row + dy - 2;
        if ((unsigned)r < 256u) {
            const float* yr = yc + r * 256;
#pragma unroll
            for (int dx = 0; dx < 5; ++dx) {
                int cc = col + dx - 2;
                float v = ((unsigned)cc < 256u) ? yr[cc] : 0.f;
                acc += kk[dy * 5 + dx] * v;
            }
        }
    }
    x1o[(size_t)bc * 65536 + row * 256 + col] = acc;
}

// ---------------- K5: fused fsas + final conv, one 8x8 patch per block ----------------
// Weights come in SGPRs via wave-uniform loads from transposed copies (hwT/owT/lwT).
// LDS 63.5 KB: x2t[48][100] (-> LN partials), hbuf[48][100] (-> outb[48][64]),
//              qbuf[48][64] (-> sbuf), kbuf[48][64] (-> x2o), pstat[128].
__global__ __launch_bounds__(512, 4) void k_fsas(const float* __restrict__ x,
                                                 const float* __restrict__ hwT, const float* __restrict__ hid_b,
                                                 const float* __restrict__ dw_w, const float* __restrict__ dw_b,
                                                 const float* __restrict__ ln_w, const float* __restrict__ ln_b,
                                                 const float* __restrict__ owT, const float* __restrict__ out_b,
                                                 const float* __restrict__ lwT, const float* __restrict__ last_b,
                                                 const float* __restrict__ x1o, float* __restrict__ out) {
    __shared__ __align__(16) float x2t[4800];
    __shared__ __align__(16) float hbuf[4800];
    __shared__ __align__(16) float qbuf[3072];
    __shared__ __align__(16) float kbuf[3072];
    __shared__ __align__(16) float pstat[128];
    float* lnp = x2t;            // overlay: x2t dead after v-phase GEMM
    float* outb = hbuf;          // overlay: hbuf dead after v-phase dw

    int tid = threadIdx.x;
    int lane = tid & 63;
    int wave = __builtin_amdgcn_readfirstlane(tid >> 6);
    int bid = blockIdx.x;
    int b = bid >> 10;
    int rem = bid & 1023;
    int row0 = (rem >> 5) << 3, col0 = (rem & 31) << 3;

    // ---- stage 1: load x2 halo tile (zero-padded) ----
    for (int i = tid; i < 4800; i += 512) {
        int c = i / 100, p = i - c * 100;
        int y = p / 10, xx = p - y * 10;
        int gy = row0 - 1 + y, gx = col0 - 1 + xx;
        float v = 0.f;
        if ((unsigned)gy < 256u && (unsigned)gx < 256u)
            v = x[((size_t)(b * 64 + 16 + c) << 16) + (gy << 8) + gx];
        x2t[i] = v;
    }
    // per-lane halo-slot geometry (slot0 = pixel lane, slot1 = pixel 64+lane)
    int y0 = lane / 10, xx0 = lane - y0 * 10;
    bool inb0 = ((unsigned)(row0 - 1 + y0) < 256u) && ((unsigned)(col0 - 1 + xx0) < 256u);
    int pp1 = 64 + lane;
    bool v1 = pp1 < 100;
    int p1 = v1 ? pp1 : 99;
    int y1i = p1 / 10, xx1 = p1 - y1i * 10;
    bool inb1 = ((unsigned)(row0 - 1 + y1i) < 256u) && ((unsigned)(col0 - 1 + xx1) < 256u);
    __syncthreads();

    float vreg[6];
    // ---- stage 2: hidden conv1x1 (48->144, SGPR weights) + dw 3x3, phases q/k/v ----
#pragma unroll 1
    for (int ph = 0; ph < 3; ++ph) {
        int c0 = ph * 48 + wave * 6;
        float acc0[6], acc1[6];
#pragma unroll
        for (int u = 0; u < 6; ++u) { float bb = hid_b[c0 + u]; acc0[u] = bb; acc1[u] = bb; }
#pragma unroll 4
        for (int ci = 0; ci < 48; ++ci) {
            float xa = x2t[ci * 100 + lane];
            float xb = x2t[ci * 100 + p1];
            const float* wr = hwT + ci * 144 + c0;
#pragma unroll
            for (int u = 0; u < 6; ++u) {
                float w = wr[u];
                acc0[u] += w * xa;
                acc1[u] += w * xb;
            }
        }
        int cl0 = wave * 6;
#pragma unroll
        for (int u = 0; u < 6; ++u) {
            hbuf[(cl0 + u) * 100 + lane] = inb0 ? acc0[u] : 0.f;
            if (v1) hbuf[(cl0 + u) * 100 + pp1] = inb1 ? acc1[u] : 0.f;
        }
        __syncthreads();
        // depthwise 3x3 over halo
        {
            int yy = lane >> 3, xd = lane & 7;
#pragma unroll
            for (int u = 0; u < 6; ++u) {
                int cl = cl0 + u, c = ph * 48 + cl;
                const float* dwp = dw_w + c * 9;
                const float* hb = hbuf + cl * 100 + yy * 10 + xd;
                float a = dw_b[c];
#pragma unroll
                for (int dy = 0; dy < 3; ++dy)
#pragma unroll
                    for (int dx = 0; dx < 3; ++dx)
                        a += dwp[dy * 3 + dx] * hb[dy * 10 + dx];
                if (ph == 0) qbuf[cl * 64 + lane] = a;
                else if (ph == 1) kbuf[cl * 64 + lane] = a;
                else vreg[u] = a;
            }
        }
        __syncthreads();
    }

    // ---- stage 3: 8x8 circular convolution out = q (*) k ----
    if (tid < 384) {
        int ch = tid >> 3, m = tid & 7;
        const float* qr = qbuf + ch * 64;
        const float* kr = kbuf + ch * 64;
        float co[8];
#pragma unroll
        for (int n = 0; n < 8; ++n) co[n] = 0.f;
#pragma unroll
        for (int i8 = 0; i8 < 8; ++i8) {
            int r = (m - i8) & 7;
            float4 ka = *(const float4*)(kr + r * 8);
            float4 kb4 = *(const float4*)(kr + r * 8 + 4);
            float kg[8] = {ka.x, ka.y, ka.z, ka.w, kb4.x, kb4.y, kb4.z, kb4.w};
            float4 qa = *(const float4*)(qr + i8 * 8);
            float4 qb4 = *(const float4*)(qr + i8 * 8 + 4);
            float qg[8] = {qa.x, qa.y, qa.z, qa.w, qb4.x, qb4.y, qb4.z, qb4.w};
#pragma unroll
            for (int j = 0; j < 8; ++j)
#pragma unroll
                for (int n = 0; n < 8; ++n)
                    co[n] += qg[j] * kg[(n - j) & 7];
        }
#pragma unroll
        for (int n = 0; n < 8; ++n) outb[ch * 64 + m * 8 + n] = co[n];
    }
    __syncthreads();

    // ---- stage 4a: layernorm stats, 256-thread parallel ----
    if (tid < 256) {
        int px = tid & 63, g = tid >> 6;
        float s = 0.f, ss = 0.f;
#pragma unroll
        for (int c = 0; c < 12; ++c) {
            float v = outb[(g * 12 + c) * 64 + px];
            s += v; ss += v * v;
        }
        lnp[(g << 6) + px] = s;
        lnp[256 + (g << 6) + px] = ss;
    }
    __syncthreads();
    if (tid < 64) {
        float s = lnp[tid] + lnp[64 + tid] + lnp[128 + tid] + lnp[192 + tid];
        float ss = lnp[256 + tid] + lnp[320 + tid] + lnp[384 + tid] + lnp[448 + tid];
        float mu = s * (1.f / 48.f);
        float var = ss * (1.f / 48.f) - mu * mu;
        pstat[tid * 2] = mu;
        pstat[tid * 2 + 1] = rsqrtf(var + 1e-6f);
    }
    __syncthreads();

    // ---- stage 4b: sbuf = v * layernorm(out) ----
    {
        float mu = pstat[lane * 2], inv = pstat[lane * 2 + 1];
        int cl0 = wave * 6;
#pragma unroll
        for (int u = 0; u < 6; ++u) {
            int cl = cl0 + u;
            float o = outb[cl * 64 + lane];
            float lnv = ln_w[cl] * ((o - mu) * inv) + ln_b[cl];
            qbuf[cl * 64 + lane] = vreg[u] * lnv;     // sbuf
        }
    }
    __syncthreads();

    // ---- stage 5: x2o = out_w @ sbuf + out_b (SGPR weights) ----
    {
        int o0 = wave * 6;
        float acc[6];
#pragma unroll
        for (int u = 0; u < 6; ++u) acc[u] = out_b[o0 + u];
#pragma unroll 4
        for (int ci = 0; ci < 48; ++ci) {
            float s = qbuf[ci * 64 + lane];
            const float* wr = owT + ci * 48 + o0;
#pragma unroll
            for (int u = 0; u < 6; ++u) acc[u] += wr[u] * s;
        }
#pragma unroll
        for (int u = 0; u < 6; ++u) kbuf[(o0 + u) * 64 + lane] = acc[u];   // x2o
    }
    __syncthreads();

    // ---- stage 6: final conv1x1 (64->64) over [x1_out ; x2o] ----
    {
        int o0 = wave * 8;
        float acc[8];
#pragma unroll
        for (int u = 0; u < 8; ++u) acc[u] = last_b[o0 + u];
        int py = lane >> 3, pxx = lane & 7;
        size_t gpix = ((size_t)(row0 + py) << 8) + col0 + pxx;
        float xr[16];
#pragma unroll
        for (int ci = 0; ci < 16; ++ci)
            xr[ci] = x1o[((size_t)(b * 16 + ci) << 16) + gpix];
#pragma unroll
        for (int ci = 0; ci < 16; ++ci) {
            const float* wr = lwT + ci * 64 + o0;
#pragma unroll
            for (int u = 0; u < 8; ++u) acc[u] += wr[u] * xr[ci];
        }
#pragma unroll 4
        for (int ci = 0; ci < 48; ++ci) {
            float s = kbuf[ci * 64 + lane];
            const float* wr = lwT + (16 + ci) * 64 + o0;
#pragma unroll
            for (int u = 0; u < 8; ++u) acc[u] += wr[u] * s;
        }
#pragma unroll
        for (int u = 0; u < 8; ++u)
            out[((size_t)(b * 64 + o0 + u) << 16) + gpix] = acc[u];
    }
}

extern "C" void kernel_launch(void* const* d_in, const int* in_sizes, int n_in,
                              void* d_out, int out_size, void* d_ws, size_t ws_size,
                              hipStream_t stream) {
    const float* x      = (const float*)d_in[0];
    const float* dl1_w1 = (const float*)d_in[1];
    const float* dl1_b1 = (const float*)d_in[2];
    const float* dl1_w2 = (const float*)d_in[3];
    const float* dl1_b2 = (const float*)d_in[4];
    const float* dl2_w1 = (const float*)d_in[5];
    const float* dl2_b1 = (const float*)d_in[6];
    const float* dl2_w2 = (const float*)d_in[7];
    const float* dl2_b2 = (const float*)d_in[8];
    const float* hid_w  = (const float*)d_in[9];
    const float* hid_b  = (const float*)d_in[10];
    const float* dw_w   = (const float*)d_in[11];
    const float* dw_b   = (const float*)d_in[12];
    const float* ln_w   = (const float*)d_in[13];
    const float* ln_b   = (const float*)d_in[14];
    const float* out_w  = (const float*)d_in[15];
    const float* out_b  = (const float*)d_in[16];
    const float* last_w = (const float*)d_in[17];
    const float* last_b = (const float*)d_in[18];
    float* out = (float*)d_out;

    float* ws      = (float*)d_ws;
    float* pooled1 = ws;                       // 64
    float* kern1   = ws + 64;                  // 576
    float* rowsum  = ws + 1024;                // 16384
    float* kern2   = ws + 17408;               // 1600
    float* hwT     = ws + 19008;               // 6912  (48x144)
    float* owT     = ws + 25920;               // 2304  (48x48)
    float* lwT     = ws + 28224;               // 4096  (64x64) -> ends 32320
    float* y1      = ws + 32768;               // 4194304
    float* x1o     = ws + 32768 + 4194304;     // 4194304

    k_prep <<<8,     256, 0, stream>>>(hid_w, out_w, last_w, hwT, owT, lwT);
    k_pool <<<64,    256, 0, stream>>>(x, pooled1);
    k_kern1<<<1,     256, 0, stream>>>(pooled1, dl1_w1, dl1_b1, dl1_w2, dl1_b2, kern1);
    k_dw3  <<<16384, 256, 0, stream>>>(x, kern1, y1, rowsum);
    k_kern2<<<1,     256, 0, stream>>>(rowsum, dl2_w1, dl2_b1, dl2_w2, dl2_b2, kern2);
    k_dw5  <<<16384, 256, 0, stream>>>(y1, kern2, x1o);
    k_fsas <<<4096,  512, 0, stream>>>(x, hwT, hid_b, dw_w, dw_b, ln_w, ln_b,
                                       owT, out_b, lwT, last_b, x1o, out);
}

// Round 3
// 320.894 us; speedup vs baseline: 2.2789x; 1.2552x over previous
//
#include <hip/hip_runtime.h>

__device__ __forceinline__ float warpsum(float v) {
    for (int off = 32; off > 0; off >>= 1) v += __shfl_down(v, off);
    return v;
}

// ---------------- K_prep: regroup weights for wave-contiguous SGPR bursts ----------------
// hwP[g][ci][u] (g=ph*8+wave, 24 groups of 6 ch):  = hid_w[(g*6+u)*48 + ci]
// owP[g][ci][u] (8 groups of 6):                   = out_w[(g*6+u)*48 + ci]
// lwP[g][ci][u] (8 groups of 8):                   = last_w[(g*8+u)*64 + ci]
__global__ __launch_bounds__(256) void k_prep(const float* __restrict__ hid_w,
                                              const float* __restrict__ out_w,
                                              const float* __restrict__ last_w,
                                              float* __restrict__ hwP,
                                              float* __restrict__ owP,
                                              float* __restrict__ lwP) {
    int t = blockIdx.x * 256 + threadIdx.x;
    int stride = gridDim.x * 256;
    for (int i = t; i < 6912; i += stride) {
        int g = i / 288, r = i - g * 288;
        int ci = r / 6, u = r - ci * 6;
        hwP[i] = hid_w[(g * 6 + u) * 48 + ci];
    }
    for (int i = t; i < 2304; i += stride) {
        int g = i / 288, r = i - g * 288;
        int ci = r / 6, u = r - ci * 6;
        owP[i] = out_w[(g * 6 + u) * 48 + ci];
    }
    for (int i = t; i < 4096; i += stride) {
        int g = i >> 9, r = i & 511;
        int ci = r >> 3, u = r & 7;
        lwP[i] = last_w[(g * 8 + u) * 64 + ci];
    }
}

// ---------------- K0: pooled mean of x1 channels ----------------
__global__ __launch_bounds__(256) void k_pool(const float* __restrict__ x, float* __restrict__ pooled1) {
    int bid = blockIdx.x;            // 64 = b*16 + c
    int b = bid >> 4, c = bid & 15;
    const float* base = x + (size_t)(b * 64 + c) * 65536;
    float s = 0.f;
    for (int i = threadIdx.x; i < 16384; i += 256) {
        float4 v = ((const float4*)base)[i];
        s += v.x + v.y + v.z + v.w;
    }
    __shared__ float red[4];
    s = warpsum(s);
    if ((threadIdx.x & 63) == 0) red[threadIdx.x >> 6] = s;
    __syncthreads();
    if (threadIdx.x == 0) pooled1[bid] = (red[0] + red[1] + red[2] + red[3]) * (1.f / 65536.f);
}

// ---------------- K1: kern1 from pooled1 (tiny MLP) ----------------
__global__ __launch_bounds__(256) void k_kern1(const float* __restrict__ pooled1,
                                               const float* __restrict__ w1, const float* __restrict__ b1,
                                               const float* __restrict__ w2, const float* __restrict__ b2,
                                               float* __restrict__ kern1) {
    __shared__ float h[64];
    int t = threadIdx.x;
    if (t < 64) {
        int b = t >> 4, j = t & 15;
        float a = b1[j];
        for (int i = 0; i < 16; ++i) a += pooled1[b * 16 + i] * w1[j * 16 + i];
        h[t] = fmaxf(a, 0.f);
    }
    __syncthreads();
    for (int i = t; i < 576; i += 256) {      // 4 * 144
        int b = i / 144, o = i - b * 144;
        float a = b2[o];
        for (int j = 0; j < 16; ++j) a += h[b * 16 + j] * w2[o * 16 + j];
        kern1[i] = a;
    }
}

// ---------------- K2: dynamic depthwise 3x3 (8 rows/block, LDS-staged) + row sums ----------------
__global__ __launch_bounds__(256) void k_dw3(const float* __restrict__ x,
                                             const float* __restrict__ kern1,
                                             float* __restrict__ y1, float* __restrict__ rowsum) {
    __shared__ float tile[10][258];
    __shared__ float red[8][4];
    int bid = blockIdx.x;            // bc*32 + rb
    int rb = bid & 31, bc = bid >> 5;
    int b = bc >> 4, c = bc & 15;
    int row0 = rb << 3;
    int col = threadIdx.x;
    const float* xc = x + ((size_t)(b * 64 + c) << 16);
#pragma unroll
    for (int j = 0; j < 10; ++j) {
        int r = row0 - 1 + j;
        tile[j][col + 1] = ((unsigned)r < 256u) ? xc[(r << 8) + col] : 0.f;
    }
    if (col < 10) { tile[col][0] = 0.f; tile[col][257] = 0.f; }
    const float* k9 = kern1 + b * 144 + c * 9;
    float kk[9];
#pragma unroll
    for (int i = 0; i < 9; ++i) kk[i] = k9[i];
    __syncthreads();
#pragma unroll
    for (int j = 0; j < 8; ++j) {
        float acc = 0.f;
#pragma unroll
        for (int dy = 0; dy < 3; ++dy)
#pragma unroll
            for (int dx = 0; dx < 3; ++dx)
                acc += kk[dy * 3 + dx] * tile[j + dy][col + dx];
        y1[((size_t)bc << 16) + ((row0 + j) << 8) + col] = acc;
        float s = warpsum(acc);
        if ((col & 63) == 0) red[j][col >> 6] = s;
    }
    __syncthreads();
    if (col < 8) rowsum[bc * 256 + row0 + col] = red[col][0] + red[col][1] + red[col][2] + red[col][3];
}

// ---------------- K3: kern2 from row sums (tiny MLP) ----------------
__global__ __launch_bounds__(256) void k_kern2(const float* __restrict__ rowsum,
                                               const float* __restrict__ w1, const float* __restrict__ b1,
                                               const float* __restrict__ w2, const float* __restrict__ b2,
                                               float* __restrict__ kern2) {
    __shared__ float ps[256];
    __shared__ float p2[64];
    __shared__ float h[64];
    int t = threadIdx.x;
    {
        int pair = t >> 2, seg = t & 3;
        const float* rs = rowsum + pair * 256 + seg * 64;
        float s = 0.f;
        for (int j = 0; j < 64; ++j) s += rs[j];
        ps[t] = s;
    }
    __syncthreads();
    if (t < 64) p2[t] = (ps[t * 4] + ps[t * 4 + 1] + ps[t * 4 + 2] + ps[t * 4 + 3]) * (1.f / 65536.f);
    __syncthreads();
    if (t < 64) {
        int b = t >> 4, j = t & 15;
        float a = b1[j];
        for (int i = 0; i < 16; ++i) a += p2[b * 16 + i] * w1[j * 16 + i];
        h[t] = fmaxf(a, 0.f);
    }
    __syncthreads();
    for (int i = t; i < 1600; i += 256) {     // 4 * 400
        int b = i / 400, o = i - b * 400;
        float a = b2[o];
        for (int j = 0; j < 16; ++j) a += h[b * 16 + j] * w2[o * 16 + j];
        kern2[i] = a;
    }
}

// ---------------- K4: dynamic depthwise 5x5 (8 rows/block, LDS-staged) ----------------
__global__ __launch_bounds__(256) void k_dw5(const float* __restrict__ y1,
                                             const float* __restrict__ kern2,
                                             float* __restrict__ x1o) {
    __shared__ float tile[12][260];
    int bid = blockIdx.x;            // bc*32 + rb
    int rb = bid & 31, bc = bid >> 5;
    int b = bc >> 4, c = bc & 15;
    int row0 = rb << 3;
    int col = threadIdx.x;
    const float* yc = y1 + ((size_t)bc << 16);
#pragma unroll
    for (int j = 0; j < 12; ++j) {
        int r = row0 - 2 + j;
        tile[j][col + 2] = ((unsigned)r < 256u) ? yc[(r << 8) + col] : 0.f;
    }
    if (col < 12) { tile[col][0] = 0.f; tile[col][1] = 0.f; tile[col][258] = 0.f; tile[col][259] = 0.f; }
    const float* k25 = kern2 + b * 400 + c * 25;
    float kk[25];
#pragma unroll
    for (int i = 0; i < 25; ++i) kk[i] = k25[i];
    __syncthreads();
#pragma unroll
    for (int j = 0; j < 8; ++j) {
        float acc = 0.f;
#pragma unroll
        for (int dy = 0; dy < 5; ++dy)
#pragma unroll
            for (int dx = 0; dx < 5; ++dx)
                acc += kk[dy * 5 + dx] * tile[j + dy][col + dx];
        x1o[((size_t)bc << 16) + ((row0 + j) << 8) + col] = acc;
    }
}

// ---------------- K5: fused fsas + final conv, one 8x8 patch per block ----------------
// LDS 63.9 KB: x2t[48][100] (-> LN partials), hbuf[48][102] (-> outb[48][68]),
//              qbuf[48][68] (-> sbuf), kbuf[48][68] (-> x2o), pstat[128].
// Strides 68/102 chosen so ds_read_b128 bank-starts tile all 32 banks (68 == 4 mod 32).
__global__ __launch_bounds__(512, 4) void k_fsas(const float* __restrict__ x,
                                                 const float* __restrict__ hwP, const float* __restrict__ hid_b,
                                                 const float* __restrict__ dw_w, const float* __restrict__ dw_b,
                                                 const float* __restrict__ ln_w, const float* __restrict__ ln_b,
                                                 const float* __restrict__ owP, const float* __restrict__ out_b,
                                                 const float* __restrict__ lwP, const float* __restrict__ last_b,
                                                 const float* __restrict__ x1o, float* __restrict__ out) {
    __shared__ __align__(16) float x2t[4800];
    __shared__ __align__(16) float hbuf[4896];
    __shared__ __align__(16) float qbuf[3264];
    __shared__ __align__(16) float kbuf[3264];
    __shared__ __align__(16) float pstat[128];
    float* lnp = x2t;            // overlay: x2t dead after v-phase GEMM
    float* outb = hbuf;          // overlay: hbuf dead after v-phase dw

    int tid = threadIdx.x;
    int lane = tid & 63;
    int wave = __builtin_amdgcn_readfirstlane(tid >> 6);
    int bid = blockIdx.x;
    int b = bid >> 10;
    int rem = bid & 1023;
    int row0 = (rem >> 5) << 3, col0 = (rem & 31) << 3;

    // ---- early x1o register preload (consumed in stage 6; T14 issue-early) ----
    int py = lane >> 3, pxx = lane & 7;
    size_t gpix = ((size_t)(row0 + py) << 8) + col0 + pxx;
    float xr[16];
#pragma unroll
    for (int ci = 0; ci < 16; ++ci)
        xr[ci] = x1o[((size_t)(b * 16 + ci) << 16) + gpix];

    // ---- stage 1: load x2 halo tile (zero-padded) ----
    for (int i = tid; i < 4800; i += 512) {
        int c = i / 100, p = i - c * 100;
        int y = p / 10, xx = p - y * 10;
        int gy = row0 - 1 + y, gx = col0 - 1 + xx;
        float v = 0.f;
        if ((unsigned)gy < 256u && (unsigned)gx < 256u)
            v = x[((size_t)(b * 64 + 16 + c) << 16) + (gy << 8) + gx];
        x2t[i] = v;
    }
    // per-lane halo-slot geometry (slot0 = pixel lane, slot1 = pixel 64+lane)
    int y0 = lane / 10, xx0 = lane - y0 * 10;
    bool inb0 = ((unsigned)(row0 - 1 + y0) < 256u) && ((unsigned)(col0 - 1 + xx0) < 256u);
    int pp1 = 64 + lane;
    bool v1 = pp1 < 100;
    int p1 = v1 ? pp1 : 99;
    int y1i = p1 / 10, xx1 = p1 - y1i * 10;
    bool inb1 = ((unsigned)(row0 - 1 + y1i) < 256u) && ((unsigned)(col0 - 1 + xx1) < 256u);
    __syncthreads();

    float vreg[6];
    // ---- stage 2: hidden conv1x1 (48->144, burst SGPR weights) + dw 3x3, phases q/k/v ----
#pragma unroll 1
    for (int ph = 0; ph < 3; ++ph) {
        const float* wb = hwP + (ph * 8 + wave) * 288;
        int c0 = ph * 48 + wave * 6;
        float acc0[6], acc1[6];
#pragma unroll
        for (int u = 0; u < 6; ++u) { float bb = hid_b[c0 + u]; acc0[u] = bb; acc1[u] = bb; }
#pragma unroll 8
        for (int ci = 0; ci < 48; ++ci) {
            float xa = x2t[ci * 100 + lane];
            float xb = x2t[ci * 100 + p1];
            const float* wr = wb + ci * 6;
#pragma unroll
            for (int u = 0; u < 6; ++u) {
                float w = wr[u];
                acc0[u] += w * xa;
                acc1[u] += w * xb;
            }
        }
        int cl0 = wave * 6;
#pragma unroll
        for (int u = 0; u < 6; ++u) {
            hbuf[(cl0 + u) * 102 + lane] = inb0 ? acc0[u] : 0.f;
            if (v1) hbuf[(cl0 + u) * 102 + pp1] = inb1 ? acc1[u] : 0.f;
        }
        __syncthreads();
        // depthwise 3x3 over halo (dw weights are wave-uniform -> s_load)
        {
            int yy = lane >> 3, xd = lane & 7;
#pragma unroll
            for (int u = 0; u < 6; ++u) {
                int cl = cl0 + u, c = ph * 48 + cl;
                const float* dwp = dw_w + c * 9;
                const float* hb = hbuf + cl * 102 + yy * 10 + xd;
                float a = dw_b[c];
#pragma unroll
                for (int dy = 0; dy < 3; ++dy)
#pragma unroll
                    for (int dx = 0; dx < 3; ++dx)
                        a += dwp[dy * 3 + dx] * hb[dy * 10 + dx];
                if (ph == 0) qbuf[cl * 68 + lane] = a;
                else if (ph == 1) kbuf[cl * 68 + lane] = a;
                else vreg[u] = a;
            }
        }
        __syncthreads();
    }

    // ---- stage 3: 8x8 circular convolution out = q (*) k (stride-68: conflict-free b128) ----
    if (tid < 384) {
        int ch = tid >> 3, m = tid & 7;
        const float* qr = qbuf + ch * 68;
        const float* kr = kbuf + ch * 68;
        float co[8];
#pragma unroll
        for (int n = 0; n < 8; ++n) co[n] = 0.f;
#pragma unroll
        for (int i8 = 0; i8 < 8; ++i8) {
            int r = (m - i8) & 7;
            float4 ka = *(const float4*)(kr + r * 8);
            float4 kb4 = *(const float4*)(kr + r * 8 + 4);
            float kg[8] = {ka.x, ka.y, ka.z, ka.w, kb4.x, kb4.y, kb4.z, kb4.w};
            float4 qa = *(const float4*)(qr + i8 * 8);
            float4 qb4 = *(const float4*)(qr + i8 * 8 + 4);
            float qg[8] = {qa.x, qa.y, qa.z, qa.w, qb4.x, qb4.y, qb4.z, qb4.w};
#pragma unroll
            for (int j = 0; j < 8; ++j)
#pragma unroll
                for (int n = 0; n < 8; ++n)
                    co[n] += qg[j] * kg[(n - j) & 7];
        }
#pragma unroll
        for (int n = 0; n < 8; ++n) outb[ch * 68 + m * 8 + n] = co[n];
    }
    __syncthreads();

    // ---- stage 4a: layernorm stats, all 512 threads ----
    {
        int px = tid & 63, g = tid >> 6;     // 8 groups x 6 channels
        float s = 0.f, ss = 0.f;
#pragma unroll
        for (int cc = 0; cc < 6; ++cc) {
            float v = outb[(g * 6 + cc) * 68 + px];
            s += v; ss += v * v;
        }
        lnp[g * 64 + px] = s;
        lnp[512 + g * 64 + px] = ss;
    }
    __syncthreads();
    if (tid < 64) {
        float s = 0.f, ss = 0.f;
#pragma unroll
        for (int g = 0; g < 8; ++g) { s += lnp[g * 64 + tid]; ss += lnp[512 + g * 64 + tid]; }
        float mu = s * (1.f / 48.f);
        float var = ss * (1.f / 48.f) - mu * mu;
        pstat[tid * 2] = mu;
        pstat[tid * 2 + 1] = rsqrtf(var + 1e-6f);
    }
    __syncthreads();

    // ---- stage 4b: sbuf = v * layernorm(out) ----
    {
        float mu = pstat[lane * 2], inv = pstat[lane * 2 + 1];
        int cl0 = wave * 6;
#pragma unroll
        for (int u = 0; u < 6; ++u) {
            int cl = cl0 + u;
            float o = outb[cl * 68 + lane];
            float lnv = ln_w[cl] * ((o - mu) * inv) + ln_b[cl];
            qbuf[cl * 68 + lane] = vreg[u] * lnv;     // sbuf
        }
    }
    __syncthreads();

    // ---- stage 5: x2o = out_w @ sbuf + out_b (burst SGPR weights) ----
    {
        int o0 = wave * 6;
        const float* wb = owP + wave * 288;
        float acc[6];
#pragma unroll
        for (int u = 0; u < 6; ++u) acc[u] = out_b[o0 + u];
#pragma unroll 8
        for (int ci = 0; ci < 48; ++ci) {
            float s = qbuf[ci * 68 + lane];
            const float* wr = wb + ci * 6;
#pragma unroll
            for (int u = 0; u < 6; ++u) acc[u] += wr[u] * s;
        }
#pragma unroll
        for (int u = 0; u < 6; ++u) kbuf[(o0 + u) * 68 + lane] = acc[u];   // x2o
    }

    // ---- stage 6a: final conv x1-part (register xr, before barrier) ----
    int o0 = wave * 8;
    const float* lb = lwP + wave * 512;
    float acc8[8];
#pragma unroll
    for (int u = 0; u < 8; ++u) acc8[u] = last_b[o0 + u];
#pragma unroll
    for (int ci = 0; ci < 16; ++ci) {
        const float* wr = lb + ci * 8;
#pragma unroll
        for (int u = 0; u < 8; ++u) acc8[u] += wr[u] * xr[ci];
    }
    __syncthreads();

    // ---- stage 6b: final conv x2-part + store ----
#pragma unroll 8
    for (int ci = 0; ci < 48; ++ci) {
        float s = kbuf[ci * 68 + lane];
        const float* wr = lb + (16 + ci) * 8;
#pragma unroll
        for (int u = 0; u < 8; ++u) acc8[u] += wr[u] * s;
    }
#pragma unroll
    for (int u = 0; u < 8; ++u)
        out[((size_t)(b * 64 + o0 + u) << 16) + gpix] = acc8[u];
}

extern "C" void kernel_launch(void* const* d_in, const int* in_sizes, int n_in,
                              void* d_out, int out_size, void* d_ws, size_t ws_size,
                              hipStream_t stream) {
    const float* x      = (const float*)d_in[0];
    const float* dl1_w1 = (const float*)d_in[1];
    const float* dl1_b1 = (const float*)d_in[2];
    const float* dl1_w2 = (const float*)d_in[3];
    const float* dl1_b2 = (const float*)d_in[4];
    const float* dl2_w1 = (const float*)d_in[5];
    const float* dl2_b1 = (const float*)d_in[6];
    const float* dl2_w2 = (const float*)d_in[7];
    const float* dl2_b2 = (const float*)d_in[8];
    const float* hid_w  = (const float*)d_in[9];
    const float* hid_b  = (const float*)d_in[10];
    const float* dw_w   = (const float*)d_in[11];
    const float* dw_b   = (const float*)d_in[12];
    const float* ln_w   = (const float*)d_in[13];
    const float* ln_b   = (const float*)d_in[14];
    const float* out_w  = (const float*)d_in[15];
    const float* out_b  = (const float*)d_in[16];
    const float* last_w = (const float*)d_in[17];
    const float* last_b = (const float*)d_in[18];
    float* out = (float*)d_out;

    float* ws      = (float*)d_ws;
    float* pooled1 = ws;                       // 64
    float* kern1   = ws + 64;                  // 576
    float* rowsum  = ws + 1024;                // 16384
    float* kern2   = ws + 17408;               // 1600
    float* hwP     = ws + 19008;               // 6912  (24x48x6)
    float* owP     = ws + 25920;               // 2304  (8x48x6)
    float* lwP     = ws + 28224;               // 4096  (8x64x8) -> ends 32320
    float* y1      = ws + 32768;               // 4194304
    float* x1o     = ws + 32768 + 4194304;     // 4194304

    k_prep <<<8,    256, 0, stream>>>(hid_w, out_w, last_w, hwP, owP, lwP);
    k_pool <<<64,   256, 0, stream>>>(x, pooled1);
    k_kern1<<<1,    256, 0, stream>>>(pooled1, dl1_w1, dl1_b1, dl1_w2, dl1_b2, kern1);
    k_dw3  <<<2048, 256, 0, stream>>>(x, kern1, y1, rowsum);
    k_kern2<<<1,    256, 0, stream>>>(rowsum, dl2_w1, dl2_b1, dl2_w2, dl2_b2, kern2);
    k_dw5  <<<2048, 256, 0, stream>>>(y1, kern2, x1o);
    k_fsas <<<4096, 512, 0, stream>>>(x, hwP, hid_b, dw_w, dw_b, ln_w, ln_b,
                                      owP, out_b, lwP, last_b, x1o, out);
}

// Round 4
// 204.377 us; speedup vs baseline: 3.5781x; 1.5701x over previous
//
#include <hip/hip_runtime.h>

typedef _Float16 h2 __attribute__((ext_vector_type(2)));
typedef _Float16 h8 __attribute__((ext_vector_type(8)));
typedef float f4 __attribute__((ext_vector_type(4)));

#if defined(__has_builtin)
#if __has_builtin(__builtin_amdgcn_fdot2)
#define HAS_FDOT2 1
#endif
#endif

__device__ __forceinline__ float warpsum(float v) {
    for (int off = 32; off > 0; off >>= 1) v += __shfl_down(v, off);
    return v;
}

// ---------------- K_prep: fp16 weight matrices, [n][72] k-padded rows ----------------
// hwH  [144][72] : hid_w[n][k], k<48 real, else 0
// owlwH: owH [48][72] (out_w) followed by lwH [64][72] (last_w, k<64 real)
__global__ __launch_bounds__(256) void k_prep(const float* __restrict__ hid_w,
                                              const float* __restrict__ out_w,
                                              const float* __restrict__ last_w,
                                              _Float16* __restrict__ hwH,
                                              _Float16* __restrict__ owlwH) {
    int t = blockIdx.x * 256 + threadIdx.x;
    int stride = gridDim.x * 256;
    for (int i = t; i < 10368; i += stride) {           // 144*72
        int n = i / 72, k = i - n * 72;
        hwH[i] = (k < 48) ? (_Float16)hid_w[n * 48 + k] : (_Float16)0.f;
    }
    for (int i = t; i < 3456; i += stride) {            // 48*72
        int n = i / 72, k = i - n * 72;
        owlwH[i] = (k < 48) ? (_Float16)out_w[n * 48 + k] : (_Float16)0.f;
    }
    for (int i = t; i < 4608; i += stride) {            // 64*72
        int n = i / 72, k = i - n * 72;
        owlwH[3456 + i] = (k < 64) ? (_Float16)last_w[n * 64 + k] : (_Float16)0.f;
    }
}

// ---------------- K0: pooled mean of x1 channels ----------------
__global__ __launch_bounds__(256) void k_pool(const float* __restrict__ x, float* __restrict__ pooled1) {
    int bid = blockIdx.x;            // 64 = b*16 + c
    int b = bid >> 4, c = bid & 15;
    const float* base = x + (size_t)(b * 64 + c) * 65536;
    float s = 0.f;
    for (int i = threadIdx.x; i < 16384; i += 256) {
        float4 v = ((const float4*)base)[i];
        s += v.x + v.y + v.z + v.w;
    }
    __shared__ float red[4];
    s = warpsum(s);
    if ((threadIdx.x & 63) == 0) red[threadIdx.x >> 6] = s;
    __syncthreads();
    if (threadIdx.x == 0) pooled1[bid] = (red[0] + red[1] + red[2] + red[3]) * (1.f / 65536.f);
}

// ---------------- K1: kern1 from pooled1 (tiny MLP) ----------------
__global__ __launch_bounds__(256) void k_kern1(const float* __restrict__ pooled1,
                                               const float* __restrict__ w1, const float* __restrict__ b1,
                                               const float* __restrict__ w2, const float* __restrict__ b2,
                                               float* __restrict__ kern1) {
    __shared__ float h[64];
    int t = threadIdx.x;
    if (t < 64) {
        int b = t >> 4, j = t & 15;
        float a = b1[j];
        for (int i = 0; i < 16; ++i) a += pooled1[b * 16 + i] * w1[j * 16 + i];
        h[t] = fmaxf(a, 0.f);
    }
    __syncthreads();
    for (int i = t; i < 576; i += 256) {      // 4 * 144
        int b = i / 144, o = i - b * 144;
        float a = b2[o];
        for (int j = 0; j < 16; ++j) a += h[b * 16 + j] * w2[o * 16 + j];
        kern1[i] = a;
    }
}

// ---------------- K2: dynamic depthwise 3x3 (8 rows/block, LDS-staged) + row sums ----------------
__global__ __launch_bounds__(256) void k_dw3(const float* __restrict__ x,
                                             const float* __restrict__ kern1,
                                             float* __restrict__ y1, float* __restrict__ rowsum) {
    __shared__ float tile[10][258];
    __shared__ float red[8][4];
    int bid = blockIdx.x;            // bc*32 + rb
    int rb = bid & 31, bc = bid >> 5;
    int b = bc >> 4, c = bc & 15;
    int row0 = rb << 3;
    int col = threadIdx.x;
    const float* xc = x + ((size_t)(b * 64 + c) << 16);
#pragma unroll
    for (int j = 0; j < 10; ++j) {
        int r = row0 - 1 + j;
        tile[j][col + 1] = ((unsigned)r < 256u) ? xc[(r << 8) + col] : 0.f;
    }
    if (col < 10) { tile[col][0] = 0.f; tile[col][257] = 0.f; }
    const float* k9 = kern1 + b * 144 + c * 9;
    float kk[9];
#pragma unroll
    for (int i = 0; i < 9; ++i) kk[i] = k9[i];
    __syncthreads();
#pragma unroll
    for (int j = 0; j < 8; ++j) {
        float acc = 0.f;
#pragma unroll
        for (int dy = 0; dy < 3; ++dy)
#pragma unroll
            for (int dx = 0; dx < 3; ++dx)
                acc += kk[dy * 3 + dx] * tile[j + dy][col + dx];
        y1[((size_t)bc << 16) + ((row0 + j) << 8) + col] = acc;
        float s = warpsum(acc);
        if ((col & 63) == 0) red[j][col >> 6] = s;
    }
    __syncthreads();
    if (col < 8) rowsum[bc * 256 + row0 + col] = red[col][0] + red[col][1] + red[col][2] + red[col][3];
}

// ---------------- K3: kern2 from row sums (tiny MLP) ----------------
__global__ __launch_bounds__(256) void k_kern2(const float* __restrict__ rowsum,
                                               const float* __restrict__ w1, const float* __restrict__ b1,
                                               const float* __restrict__ w2, const float* __restrict__ b2,
                                               float* __restrict__ kern2) {
    __shared__ float ps[256];
    __shared__ float p2[64];
    __shared__ float h[64];
    int t = threadIdx.x;
    {
        int pair = t >> 2, seg = t & 3;
        const float* rs = rowsum + pair * 256 + seg * 64;
        float s = 0.f;
        for (int j = 0; j < 64; ++j) s += rs[j];
        ps[t] = s;
    }
    __syncthreads();
    if (t < 64) p2[t] = (ps[t * 4] + ps[t * 4 + 1] + ps[t * 4 + 2] + ps[t * 4 + 3]) * (1.f / 65536.f);
    __syncthreads();
    if (t < 64) {
        int b = t >> 4, j = t & 15;
        float a = b1[j];
        for (int i = 0; i < 16; ++i) a += p2[b * 16 + i] * w1[j * 16 + i];
        h[t] = fmaxf(a, 0.f);
    }
    __syncthreads();
    for (int i = t; i < 1600; i += 256) {     // 4 * 400
        int b = i / 400, o = i - b * 400;
        float a = b2[o];
        for (int j = 0; j < 16; ++j) a += h[b * 16 + j] * w2[o * 16 + j];
        kern2[i] = a;
    }
}

// ---------------- K4: dynamic depthwise 5x5 (8 rows/block, LDS-staged) ----------------
__global__ __launch_bounds__(256) void k_dw5(const float* __restrict__ y1,
                                             const float* __restrict__ kern2,
                                             float* __restrict__ x1o) {
    __shared__ float tile[12][260];
    int bid = blockIdx.x;            // bc*32 + rb
    int rb = bid & 31, bc = bid >> 5;
    int b = bc >> 4, c = bc & 15;
    int row0 = rb << 3;
    int col = threadIdx.x;
    const float* yc = y1 + ((size_t)bc << 16);
#pragma unroll
    for (int j = 0; j < 12; ++j) {
        int r = row0 - 2 + j;
        tile[j][col + 2] = ((unsigned)r < 256u) ? yc[(r << 8) + col] : 0.f;
    }
    if (col < 12) { tile[col][0] = 0.f; tile[col][1] = 0.f; tile[col][258] = 0.f; tile[col][259] = 0.f; }
    const float* k25 = kern2 + b * 400 + c * 25;
    float kk[25];
#pragma unroll
    for (int i = 0; i < 25; ++i) kk[i] = k25[i];
    __syncthreads();
#pragma unroll
    for (int j = 0; j < 8; ++j) {
        float acc = 0.f;
#pragma unroll
        for (int dy = 0; dy < 5; ++dy)
#pragma unroll
            for (int dx = 0; dx < 5; ++dx)
                acc += kk[dy * 5 + dx] * tile[j + dy][col + dx];
        x1o[((size_t)bc << 16) + ((row0 + j) << 8) + col] = acc;
    }
}

// ---------------- K5: fused fsas + final conv (fp16 MFMA), one 8x8 patch per block ----------------
// LDS 62.7 KB:
//  Abuf  [112][72] f16 : x2 halo tile, MFMA-A layout (px-major). Overlays: fbuf [64][72] (elems 0..4607),
//                        lnp f32[1024] (elems 4608..6655).
//  wbuf  [8064] f16    : per-phase hid weights [48][72]; later ow[48][72] + lw[64][72].
//  hbuf  [48][104] f16 : hidden halo per phase. Overlays: outb [48][72], cbuf [64][72].
//  qbuf  [48][72] f16  : q rows.
//  kbuf2 [48][136] f16 : per (ch,row): krev[8] | krevrot[8]. Overlays: sbufA [64][72].
__global__ __launch_bounds__(512, 4) void k_fsas(const float* __restrict__ x,
                                                 const _Float16* __restrict__ hwH, const float* __restrict__ hid_b,
                                                 const float* __restrict__ dw_w, const float* __restrict__ dw_b,
                                                 const float* __restrict__ ln_w, const float* __restrict__ ln_b,
                                                 const _Float16* __restrict__ owlwH, const float* __restrict__ out_b,
                                                 const float* __restrict__ last_b,
                                                 const float* __restrict__ x1o, float* __restrict__ out) {
    __shared__ __align__(16) _Float16 Abuf[8064];
    __shared__ __align__(16) _Float16 wbuf[8064];
    __shared__ __align__(16) _Float16 hbuf[4992];
    __shared__ __align__(16) _Float16 qbuf[3456];
    __shared__ __align__(16) _Float16 kbuf2[6528];
    __shared__ __align__(16) float pstat[128];

    _Float16* fbuf  = Abuf;
    float*    lnp   = (float*)(Abuf + 4608);
    _Float16* outb  = hbuf;
    _Float16* cbuf  = hbuf;
    _Float16* sbufA = kbuf2;

    int tid = threadIdx.x;
    int lane = tid & 63;
    int wave = __builtin_amdgcn_readfirstlane(tid >> 6);
    int bid = blockIdx.x;
    int swz = ((bid & 7) << 9) | (bid >> 3);        // bijective XCD swizzle (4096 = 8*512)
    int b = swz >> 10;
    int rem = swz & 1023;
    int row0 = (rem >> 5) << 3, col0 = (rem & 31) << 3;

    int px2 = tid & 63, pr = tid >> 6;
    size_t gpix2 = ((size_t)(row0 + (px2 >> 3)) << 8) + col0 + (px2 & 7);

    // ---- stage 0: zero A, stage phase-0 weights ----
    for (int j = tid; j < 4032; j += 512) ((unsigned int*)Abuf)[j] = 0u;
    for (int i = tid; i < 1728; i += 512) ((unsigned int*)wbuf)[i] = ((const unsigned int*)hwH)[i];
    __syncthreads();

    // ---- stage 1: fill A = x2 halo tile (coalesced per channel), fp16 ----
    for (int j = tid; j < 4800; j += 512) {
        int k = j / 100, p = j - k * 100;
        int yv = p / 10, xv = p - yv * 10;
        int gy = row0 - 1 + yv, gx = col0 - 1 + xv;
        if ((unsigned)gy < 256u && (unsigned)gx < 256u)
            Abuf[p * 72 + k] = (_Float16)x[((size_t)(b * 64 + 16 + k) << 16) + (gy << 8) + gx];
    }
    __syncthreads();

    float vreg[6];
    // ---- stage 2: hidden conv1x1 via MFMA + dw3x3, phases q/k/v ----
#pragma unroll 1
    for (int ph = 0; ph < 3; ++ph) {
        // GEMM: C[112 px][48 ch] = A[112][48] @ W[48][48-slice]
        if (wave < 7) {
            int mt = wave;
            int fr = (lane & 15) * 72 + ((lane >> 4) << 3);
            h8 a0 = *(const h8*)(Abuf + mt * 1152 + fr);
            h8 a1 = *(const h8*)(Abuf + mt * 1152 + 32 + fr);
#pragma unroll
            for (int nt = 0; nt < 3; ++nt) {
                h8 b0 = *(const h8*)(wbuf + nt * 1152 + fr);
                h8 b1 = *(const h8*)(wbuf + nt * 1152 + 32 + fr);
                float bias = hid_b[ph * 48 + nt * 16 + (lane & 15)];
                f4 acc = {bias, bias, bias, bias};
                acc = __builtin_amdgcn_mfma_f32_16x16x32_f16(a0, b0, acc, 0, 0, 0);
                acc = __builtin_amdgcn_mfma_f32_16x16x32_f16(a1, b1, acc, 0, 0, 0);
                int n_l = nt * 16 + (lane & 15);
                int mb = mt * 16 + ((lane >> 4) << 2);
#pragma unroll
                for (int r = 0; r < 4; ++r) {
                    int m = mb + r;
                    if (m < 104) {
                        bool ok = (m < 100);
                        if (ok) {
                            int yv = m / 10, xv = m - yv * 10;
                            ok = ((unsigned)(row0 - 1 + yv) < 256u) && ((unsigned)(col0 - 1 + xv) < 256u);
                        }
                        hbuf[n_l * 104 + m] = ok ? (_Float16)acc[r] : (_Float16)0.f;
                    }
                }
            }
        }
        __syncthreads();
        // depthwise 3x3 over fp16 halo
        {
            int yy = lane >> 3, xd = lane & 7;
            int cl0 = wave * 6;
#pragma unroll
            for (int u = 0; u < 6; ++u) {
                int cl = cl0 + u, c = ph * 48 + cl;
                const float* dwp = dw_w + c * 9;
                const _Float16* hb = hbuf + cl * 104 + yy * 10 + xd;
                float a = dw_b[c];
#pragma unroll
                for (int dy = 0; dy < 3; ++dy)
#pragma unroll
                    for (int dx = 0; dx < 3; ++dx)
                        a += dwp[dy * 3 + dx] * (float)hb[dy * 10 + dx];
                if (ph == 0) qbuf[cl * 72 + lane] = (_Float16)a;
                else if (ph == 1) {
                    int jj = lane & 7;
                    kbuf2[cl * 136 + yy * 16 + ((8 - jj) & 7)] = (_Float16)a;       // krev
                    kbuf2[cl * 136 + yy * 16 + 8 + ((9 - jj) & 7)] = (_Float16)a;   // krevrot1
                } else vreg[u] = a;
            }
        }
        if (ph < 2) {   // stage next phase weights
            const unsigned int* src = (const unsigned int*)(hwH + (ph + 1) * 3456);
            for (int i = tid; i < 1728; i += 512) ((unsigned int*)wbuf)[i] = src[i];
        }
        __syncthreads();
    }

    // ---- x1o early loads (consumed into fbuf below) ----
    float xa = x1o[((size_t)(b * 16 + 2 * pr) << 16) + gpix2];
    float xb = x1o[((size_t)(b * 16 + 2 * pr + 1) << 16) + gpix2];

    // ---- stage 3: 8x8 circular convolution via dot2 (waves 0-5); waves 6-7 stage ow/lw ----
    if (tid < 384) {
        int ch = tid >> 3, m = tid & 7;
        float co[8];
#pragma unroll
        for (int n = 0; n < 8; ++n) co[n] = 0.f;
#pragma unroll
        for (int i8 = 0; i8 < 8; ++i8) {
            int r = (m - i8) & 7;
            h8 q8 = *(const h8*)(qbuf + ch * 72 + i8 * 8);
            h8 e8 = *(const h8*)(kbuf2 + ch * 136 + r * 16);
#ifdef HAS_FDOT2
            h8 o8 = *(const h8*)(kbuf2 + ch * 136 + r * 16 + 8);
            h2 qp[4], ep[4], op[4];
            qp[0] = __builtin_shufflevector(q8, q8, 0, 1); qp[1] = __builtin_shufflevector(q8, q8, 2, 3);
            qp[2] = __builtin_shufflevector(q8, q8, 4, 5); qp[3] = __builtin_shufflevector(q8, q8, 6, 7);
            ep[0] = __builtin_shufflevector(e8, e8, 0, 1); ep[1] = __builtin_shufflevector(e8, e8, 2, 3);
            ep[2] = __builtin_shufflevector(e8, e8, 4, 5); ep[3] = __builtin_shufflevector(e8, e8, 6, 7);
            op[0] = __builtin_shufflevector(o8, o8, 0, 1); op[1] = __builtin_shufflevector(o8, o8, 2, 3);
            op[2] = __builtin_shufflevector(o8, o8, 4, 5); op[3] = __builtin_shufflevector(o8, o8, 6, 7);
#pragma unroll
            for (int u = 0; u < 4; ++u)
#pragma unroll
                for (int a = 0; a < 4; ++a) {
                    co[2 * u]     = __builtin_amdgcn_fdot2(qp[a], ep[(a - u) & 3], co[2 * u], false);
                    co[2 * u + 1] = __builtin_amdgcn_fdot2(qp[a], op[(a - u) & 3], co[2 * u + 1], false);
                }
#else
            float qf[8], kf[8];
#pragma unroll
            for (int j = 0; j < 8; ++j) { qf[j] = (float)q8[j]; kf[j] = (float)e8[(8 - j) & 7]; }
#pragma unroll
            for (int j = 0; j < 8; ++j)
#pragma unroll
                for (int n = 0; n < 8; ++n)
                    co[n] += qf[j] * kf[(n - j) & 7];
#endif
        }
#pragma unroll
        for (int v = 0; v < 4; ++v)
            *(h2*)(outb + ch * 72 + m * 8 + 2 * v) = (h2){(_Float16)co[2 * v], (_Float16)co[2 * v + 1]};
    } else {
        for (int j = tid - 384; j < 4032; j += 128)
            ((unsigned int*)wbuf)[j] = ((const unsigned int*)owlwH)[j];
    }
    // fbuf x1 part (fp16)
    *(h2*)(fbuf + px2 * 72 + 2 * pr) = (h2){(_Float16)xa, (_Float16)xb};
    __syncthreads();

    // ---- stage 4a: layernorm stats ----
    {
        float s = 0.f, ss = 0.f;
#pragma unroll
        for (int cc = 0; cc < 6; ++cc) {
            float v = (float)outb[(pr * 6 + cc) * 72 + px2];
            s += v; ss += v * v;
        }
        lnp[pr * 64 + px2] = s;
        lnp[512 + pr * 64 + px2] = ss;
    }
    __syncthreads();
    if (tid < 64) {
        float s = 0.f, ss = 0.f;
#pragma unroll
        for (int g = 0; g < 8; ++g) { s += lnp[g * 64 + tid]; ss += lnp[512 + g * 64 + tid]; }
        float mu = s * (1.f / 48.f);
        float var = ss * (1.f / 48.f) - mu * mu;
        pstat[tid * 2] = mu;
        pstat[tid * 2 + 1] = rsqrtf(var + 1e-6f);
    }
    __syncthreads();

    // ---- stage 4b: sbufA[px][ch] = v * layernorm(out), fp16; zero K-pad cols 48..63 ----
    {
        float mu = pstat[lane * 2], inv = pstat[lane * 2 + 1];
        int cl0 = wave * 6;
#pragma unroll
        for (int u = 0; u < 6; ++u) {
            int cl = cl0 + u;
            float o = (float)outb[cl * 72 + lane];
            float lnv = ln_w[cl] * ((o - mu) * inv) + ln_b[cl];
            sbufA[lane * 72 + cl] = (_Float16)(vreg[u] * lnv);
        }
        *(h2*)(sbufA + px2 * 72 + 48 + 2 * pr) = (h2){(_Float16)0.f, (_Float16)0.f};
    }
    __syncthreads();

    // ---- stage 5: x2o = out_w @ sbuf + out_b (MFMA) -> fbuf[px][16+n] ----
    for (int t = wave; t < 12; t += 8) {
        int mt = t / 3, nt = t - mt * 3;
        int fr = (lane & 15) * 72 + ((lane >> 4) << 3);
        h8 a0 = *(const h8*)(sbufA + mt * 1152 + fr);
        h8 a1 = *(const h8*)(sbufA + mt * 1152 + 32 + fr);
        h8 b0 = *(const h8*)(wbuf + nt * 1152 + fr);
        h8 b1 = *(const h8*)(wbuf + nt * 1152 + 32 + fr);
        float bias = out_b[nt * 16 + (lane & 15)];
        f4 acc = {bias, bias, bias, bias};
        acc = __builtin_amdgcn_mfma_f32_16x16x32_f16(a0, b0, acc, 0, 0, 0);
        acc = __builtin_amdgcn_mfma_f32_16x16x32_f16(a1, b1, acc, 0, 0, 0);
        int n5 = nt * 16 + (lane & 15);
        int pb = mt * 16 + ((lane >> 4) << 2);
#pragma unroll
        for (int r = 0; r < 4; ++r)
            fbuf[(pb + r) * 72 + 16 + n5] = (_Float16)acc[r];
    }
    __syncthreads();

    // ---- stage 6: out = last_w @ [x1;x2o] + last_b (MFMA) -> cbuf[ch][px] ----
    for (int t = wave; t < 16; t += 8) {
        int mt = t >> 2, nt = t & 3;
        int fr = (lane & 15) * 72 + ((lane >> 4) << 3);
        h8 a0 = *(const h8*)(fbuf + mt * 1152 + fr);
        h8 a1 = *(const h8*)(fbuf + mt * 1152 + 32 + fr);
        h8 b0 = *(const h8*)(wbuf + 3456 + nt * 1152 + fr);
        h8 b1 = *(const h8*)(wbuf + 3456 + nt * 1152 + 32 + fr);
        float bias = last_b[nt * 16 + (lane & 15)];
        f4 acc = {bias, bias, bias, bias};
        acc = __builtin_amdgcn_mfma_f32_16x16x32_f16(a0, b0, acc, 0, 0, 0);
        acc = __builtin_amdgcn_mfma_f32_16x16x32_f16(a1, b1, acc, 0, 0, 0);
        int ch = nt * 16 + (lane & 15);
        int pb = mt * 16 + ((lane >> 4) << 2);
#pragma unroll
        for (int r = 0; r < 4; ++r)
            cbuf[ch * 72 + pb + r] = (_Float16)acc[r];
    }
    __syncthreads();

    // ---- stage 7: store ----
#pragma unroll
    for (int u = 0; u < 8; ++u) {
        int ch = pr * 8 + u;
        out[((size_t)(b * 64 + ch) << 16) + gpix2] = (float)cbuf[ch * 72 + px2];
    }
}

extern "C" void kernel_launch(void* const* d_in, const int* in_sizes, int n_in,
                              void* d_out, int out_size, void* d_ws, size_t ws_size,
                              hipStream_t stream) {
    const float* x      = (const float*)d_in[0];
    const float* dl1_w1 = (const float*)d_in[1];
    const float* dl1_b1 = (const float*)d_in[2];
    const float* dl1_w2 = (const float*)d_in[3];
    const float* dl1_b2 = (const float*)d_in[4];
    const float* dl2_w1 = (const float*)d_in[5];
    const float* dl2_b1 = (const float*)d_in[6];
    const float* dl2_w2 = (const float*)d_in[7];
    const float* dl2_b2 = (const float*)d_in[8];
    const float* hid_w  = (const float*)d_in[9];
    const float* hid_b  = (const float*)d_in[10];
    const float* dw_w   = (const float*)d_in[11];
    const float* dw_b   = (const float*)d_in[12];
    const float* ln_w   = (const float*)d_in[13];
    const float* ln_b   = (const float*)d_in[14];
    const float* out_w  = (const float*)d_in[15];
    const float* out_b  = (const float*)d_in[16];
    const float* last_w = (const float*)d_in[17];
    const float* last_b = (const float*)d_in[18];
    float* out = (float*)d_out;

    float* ws      = (float*)d_ws;
    float* pooled1 = ws;                       // 64
    float* kern1   = ws + 64;                  // 576
    float* rowsum  = ws + 1024;                // 16384
    float* kern2   = ws + 17408;               // 1600
    _Float16* hwH   = (_Float16*)(ws + 19008); // 10368 fp16 = 5184 floats
    _Float16* owlwH = (_Float16*)(ws + 24192); // 8064 fp16 = 4032 floats -> ends 28224
    float* y1      = ws + 32768;               // 4194304
    float* x1o     = ws + 32768 + 4194304;     // 4194304

    k_prep <<<8,    256, 0, stream>>>(hid_w, out_w, last_w, hwH, owlwH);
    k_pool <<<64,   256, 0, stream>>>(x, pooled1);
    k_kern1<<<1,    256, 0, stream>>>(pooled1, dl1_w1, dl1_b1, dl1_w2, dl1_b2, kern1);
    k_dw3  <<<2048, 256, 0, stream>>>(x, kern1, y1, rowsum);
    k_kern2<<<1,    256, 0, stream>>>(rowsum, dl2_w1, dl2_b1, dl2_w2, dl2_b2, kern2);
    k_dw5  <<<2048, 256, 0, stream>>>(y1, kern2, x1o);
    k_fsas <<<4096, 512, 0, stream>>>(x, hwH, hid_b, dw_w, dw_b, ln_w, ln_b,
                                      owlwH, out_b, last_b, x1o, out);
}

// Round 5
// 179.802 us; speedup vs baseline: 4.0671x; 1.1367x over previous
//
#include <hip/hip_runtime.h>

typedef _Float16 h2 __attribute__((ext_vector_type(2)));
typedef _Float16 h4 __attribute__((ext_vector_type(4)));
typedef _Float16 h8 __attribute__((ext_vector_type(8)));
typedef float f4 __attribute__((ext_vector_type(4)));

#if defined(__has_builtin)
#if __has_builtin(__builtin_amdgcn_fdot2)
#define HAS_FDOT2 1
#endif
#endif

__device__ __forceinline__ float warpsum(float v) {
    for (int off = 32; off > 0; off >>= 1) v += __shfl_down(v, off);
    return v;
}

// ---------------- K_prep: fp16 weight matrices, [n][72] k-padded rows ----------------
__global__ __launch_bounds__(256) void k_prep(const float* __restrict__ hid_w,
                                              const float* __restrict__ out_w,
                                              const float* __restrict__ last_w,
                                              _Float16* __restrict__ hwH,
                                              _Float16* __restrict__ owlwH) {
    int t = blockIdx.x * 256 + threadIdx.x;
    int stride = gridDim.x * 256;
    for (int i = t; i < 10368; i += stride) {           // 144*72
        int n = i / 72, k = i - n * 72;
        hwH[i] = (k < 48) ? (_Float16)hid_w[n * 48 + k] : (_Float16)0.f;
    }
    for (int i = t; i < 3456; i += stride) {            // 48*72
        int n = i / 72, k = i - n * 72;
        owlwH[i] = (k < 48) ? (_Float16)out_w[n * 48 + k] : (_Float16)0.f;
    }
    for (int i = t; i < 4608; i += stride) {            // 64*72
        int n = i / 72, k = i - n * 72;
        owlwH[3456 + i] = (k < 64) ? (_Float16)last_w[n * 64 + k] : (_Float16)0.f;
    }
}

// ---------------- K0: pooled mean of x1 channels ----------------
__global__ __launch_bounds__(256) void k_pool(const float* __restrict__ x, float* __restrict__ pooled1) {
    int bid = blockIdx.x;            // 64 = b*16 + c
    int b = bid >> 4, c = bid & 15;
    const float* base = x + (size_t)(b * 64 + c) * 65536;
    float s = 0.f;
    for (int i = threadIdx.x; i < 16384; i += 256) {
        float4 v = ((const float4*)base)[i];
        s += v.x + v.y + v.z + v.w;
    }
    __shared__ float red[4];
    s = warpsum(s);
    if ((threadIdx.x & 63) == 0) red[threadIdx.x >> 6] = s;
    __syncthreads();
    if (threadIdx.x == 0) pooled1[bid] = (red[0] + red[1] + red[2] + red[3]) * (1.f / 65536.f);
}

// ---------------- K1: kern1 from pooled1 (tiny MLP) ----------------
__global__ __launch_bounds__(256) void k_kern1(const float* __restrict__ pooled1,
                                               const float* __restrict__ w1, const float* __restrict__ b1,
                                               const float* __restrict__ w2, const float* __restrict__ b2,
                                               float* __restrict__ kern1) {
    __shared__ float h[64];
    int t = threadIdx.x;
    if (t < 64) {
        int b = t >> 4, j = t & 15;
        float a = b1[j];
        for (int i = 0; i < 16; ++i) a += pooled1[b * 16 + i] * w1[j * 16 + i];
        h[t] = fmaxf(a, 0.f);
    }
    __syncthreads();
    for (int i = t; i < 576; i += 256) {      // 4 * 144
        int b = i / 144, o = i - b * 144;
        float a = b2[o];
        for (int j = 0; j < 16; ++j) a += h[b * 16 + j] * w2[o * 16 + j];
        kern1[i] = a;
    }
}

// ---------------- K2: dynamic depthwise 3x3 (8 rows/block, LDS-staged) + row sums ----------------
__global__ __launch_bounds__(256) void k_dw3(const float* __restrict__ x,
                                             const float* __restrict__ kern1,
                                             float* __restrict__ y1, float* __restrict__ rowsum) {
    __shared__ float tile[10][258];
    __shared__ float red[8][4];
    int bid = blockIdx.x;            // bc*32 + rb
    int rb = bid & 31, bc = bid >> 5;
    int b = bc >> 4, c = bc & 15;
    int row0 = rb << 3;
    int col = threadIdx.x;
    const float* xc = x + ((size_t)(b * 64 + c) << 16);
#pragma unroll
    for (int j = 0; j < 10; ++j) {
        int r = row0 - 1 + j;
        tile[j][col + 1] = ((unsigned)r < 256u) ? xc[(r << 8) + col] : 0.f;
    }
    if (col < 10) { tile[col][0] = 0.f; tile[col][257] = 0.f; }
    const float* k9 = kern1 + b * 144 + c * 9;
    float kk[9];
#pragma unroll
    for (int i = 0; i < 9; ++i) kk[i] = k9[i];
    __syncthreads();
#pragma unroll
    for (int j = 0; j < 8; ++j) {
        float acc = 0.f;
#pragma unroll
        for (int dy = 0; dy < 3; ++dy)
#pragma unroll
            for (int dx = 0; dx < 3; ++dx)
                acc += kk[dy * 3 + dx] * tile[j + dy][col + dx];
        y1[((size_t)bc << 16) + ((row0 + j) << 8) + col] = acc;
        float s = warpsum(acc);
        if ((col & 63) == 0) red[j][col >> 6] = s;
    }
    __syncthreads();
    if (col < 8) rowsum[bc * 256 + row0 + col] = red[col][0] + red[col][1] + red[col][2] + red[col][3];
}

// ---------------- K3: kern2 from row sums (tiny MLP) ----------------
__global__ __launch_bounds__(256) void k_kern2(const float* __restrict__ rowsum,
                                               const float* __restrict__ w1, const float* __restrict__ b1,
                                               const float* __restrict__ w2, const float* __restrict__ b2,
                                               float* __restrict__ kern2) {
    __shared__ float ps[256];
    __shared__ float p2[64];
    __shared__ float h[64];
    int t = threadIdx.x;
    {
        int pair = t >> 2, seg = t & 3;
        const float* rs = rowsum + pair * 256 + seg * 64;
        float s = 0.f;
        for (int j = 0; j < 64; ++j) s += rs[j];
        ps[t] = s;
    }
    __syncthreads();
    if (t < 64) p2[t] = (ps[t * 4] + ps[t * 4 + 1] + ps[t * 4 + 2] + ps[t * 4 + 3]) * (1.f / 65536.f);
    __syncthreads();
    if (t < 64) {
        int b = t >> 4, j = t & 15;
        float a = b1[j];
        for (int i = 0; i < 16; ++i) a += p2[b * 16 + i] * w1[j * 16 + i];
        h[t] = fmaxf(a, 0.f);
    }
    __syncthreads();
    for (int i = t; i < 1600; i += 256) {     // 4 * 400
        int b = i / 400, o = i - b * 400;
        float a = b2[o];
        for (int j = 0; j < 16; ++j) a += h[b * 16 + j] * w2[o * 16 + j];
        kern2[i] = a;
    }
}

// ---------------- K4: dynamic depthwise 5x5 (8 rows/block, LDS-staged) ----------------
__global__ __launch_bounds__(256) void k_dw5(const float* __restrict__ y1,
                                             const float* __restrict__ kern2,
                                             float* __restrict__ x1o) {
    __shared__ float tile[12][260];
    int bid = blockIdx.x;            // bc*32 + rb
    int rb = bid & 31, bc = bid >> 5;
    int b = bc >> 4, c = bc & 15;
    int row0 = rb << 3;
    int col = threadIdx.x;
    const float* yc = y1 + ((size_t)bc << 16);
#pragma unroll
    for (int j = 0; j < 12; ++j) {
        int r = row0 - 2 + j;
        tile[j][col + 2] = ((unsigned)r < 256u) ? yc[(r << 8) + col] : 0.f;
    }
    if (col < 12) { tile[col][0] = 0.f; tile[col][1] = 0.f; tile[col][258] = 0.f; tile[col][259] = 0.f; }
    const float* k25 = kern2 + b * 400 + c * 25;
    float kk[25];
#pragma unroll
    for (int i = 0; i < 25; ++i) kk[i] = k25[i];
    __syncthreads();
#pragma unroll
    for (int j = 0; j < 8; ++j) {
        float acc = 0.f;
#pragma unroll
        for (int dy = 0; dy < 5; ++dy)
#pragma unroll
            for (int dx = 0; dx < 5; ++dx)
                acc += kk[dy * 5 + dx] * tile[j + dy][col + dx];
        x1o[((size_t)bc << 16) + ((row0 + j) << 8) + col] = acc;
    }
}

// ---------------- K5: fused fsas + final conv (fp16 MFMA), one 8x8 patch per block ----------------
// LDS 51.5 KB (3 blocks/CU):
//  Abuf  [144][72] f16 : x2 halo, A-layout p=y*12+x (rows 0..119 real, 120..127 pad).
//        Overlays: fbuf [64][72] (0..4607), lnp f32[1024] (4608..6655), vbuf [48][72] (6656..10111).
//  hbuf  [48][10][12] f16 : hidden halo per phase. Overlays: outb [48][72], cbuf [64][72].
//  qbuf  [48][72] f16. kbuf2 [48][136] f16 (krev|krevrot per row). Overlay: sbufA [64][72].
// Weights (hwH/owlwH/dw_w) are loaded global->VGPR directly (L2-resident, shared by all blocks).
__global__ __launch_bounds__(512, 6) void k_fsas(const float* __restrict__ x,
                                                 const _Float16* __restrict__ hwH, const float* __restrict__ hid_b,
                                                 const float* __restrict__ dw_w, const float* __restrict__ dw_b,
                                                 const float* __restrict__ ln_w, const float* __restrict__ ln_b,
                                                 const _Float16* __restrict__ owlwH, const float* __restrict__ out_b,
                                                 const float* __restrict__ last_b,
                                                 const float* __restrict__ x1o, float* __restrict__ out) {
    __shared__ __align__(16) _Float16 Abuf[10368];
    __shared__ __align__(16) _Float16 hbuf[5760];
    __shared__ __align__(16) _Float16 qbuf[3456];
    __shared__ __align__(16) _Float16 kbuf2[6528];
    __shared__ __align__(16) float pstat[128];

    _Float16* fbuf  = Abuf;                  // [64][72]
    float*    lnp   = (float*)(Abuf + 4608); // float[1024]
    _Float16* vbuf  = Abuf + 6656;           // [48][72]
    _Float16* outb  = hbuf;                  // [48][72]
    _Float16* cbuf  = hbuf;                  // [64][72]
    _Float16* sbufA = kbuf2;                 // [64][72]

    int tid = threadIdx.x;
    int lane = tid & 63;
    int wave = __builtin_amdgcn_readfirstlane(tid >> 6);
    int bid = blockIdx.x;
    int swz = ((bid & 7) << 9) | (bid >> 3);        // bijective XCD swizzle (4096 = 8*512)
    int b = swz >> 10;
    int rem = swz & 1023;
    int row0 = (rem >> 5) << 3, col0 = (rem & 31) << 3;

    int px2 = lane, pr = wave;
    size_t gpix2 = ((size_t)(row0 + (px2 >> 3)) << 8) + col0 + (px2 & 7);

    // MFMA fragment geometry + per-row store masks (computed once)
    int l16 = lane & 15, lhi = lane >> 4;
    int fr = l16 * 72 + (lhi << 3);
    int mb = wave * 16 + (lhi << 2);
    bool st[4], vok[4];
#pragma unroll
    for (int r = 0; r < 4; ++r) {
        int m = mb + r;
        st[r] = (m < 120);
        int yv = m / 12, xv = m - yv * 12;
        vok[r] = st[r] && (xv < 10) &&
                 ((unsigned)(row0 - 1 + yv) < 256u) && ((unsigned)(col0 - 1 + xv) < 256u);
    }

    // ---- stage 0: zero A rows 0..127 ----
    for (int j = tid; j < 4608; j += 512) ((unsigned int*)Abuf)[j] = 0u;
    __syncthreads();

    // ---- stage 1: fill A = x2 halo (p = y*12+x) ----
    for (int j = tid; j < 4800; j += 512) {
        int k = j / 100, q = j - k * 100;
        int yv = q / 10, xv = q - yv * 10;
        int gy = row0 - 1 + yv, gx = col0 - 1 + xv;
        if ((unsigned)gy < 256u && (unsigned)gx < 256u)
            Abuf[(yv * 12 + xv) * 72 + k] = (_Float16)x[((size_t)(b * 64 + 16 + k) << 16) + (gy << 8) + gx];
    }
    __syncthreads();

    // A-frags: constant across phases (vbuf overlay is written only after last GEMM read)
    h8 a0 = *(const h8*)(Abuf + wave * 1152 + fr);
    h8 a1 = *(const h8*)(Abuf + wave * 1152 + 32 + fr);

    int dch = tid >> 3, drow = tid & 7;   // dw task: channel, output row (tid < 384)

    // ---- stage 2: hidden conv1x1 via MFMA (B from global) + vectorized dw3x3 ----
#pragma unroll 1
    for (int ph = 0; ph < 3; ++ph) {
        const _Float16* wp = hwH + ph * 3456;
        h8 b0[3], b1[3];
#pragma unroll
        for (int nt = 0; nt < 3; ++nt) {
            b0[nt] = *(const h8*)(wp + nt * 1152 + fr);
            b1[nt] = *(const h8*)(wp + nt * 1152 + 32 + fr);
        }
#pragma unroll
        for (int nt = 0; nt < 3; ++nt) {
            float bias = hid_b[ph * 48 + nt * 16 + l16];
            f4 acc = {bias, bias, bias, bias};
            acc = __builtin_amdgcn_mfma_f32_16x16x32_f16(a0, b0[nt], acc, 0, 0, 0);
            acc = __builtin_amdgcn_mfma_f32_16x16x32_f16(a1, b1[nt], acc, 0, 0, 0);
            int n_l = nt * 16 + l16;
#pragma unroll
            for (int r = 0; r < 4; ++r)
                if (st[r]) hbuf[n_l * 120 + mb + r] = vok[r] ? (_Float16)acc[r] : (_Float16)0.f;
        }
        __syncthreads();
        // depthwise 3x3: one (channel,row) task per thread, vector LDS reads
        if (tid < 384) {
            int c = ph * 48 + dch;
            const float* dwp = dw_w + c * 9;
            float bias = dw_b[c];
            float o[8];
#pragma unroll
            for (int xx = 0; xx < 8; ++xx) o[xx] = bias;
            const _Float16* hb = hbuf + dch * 120 + drow * 12;
#pragma unroll
            for (int dy = 0; dy < 3; ++dy) {
                h4 r0 = *(const h4*)(hb + dy * 12);
                h4 r1 = *(const h4*)(hb + dy * 12 + 4);
                h2 r2 = *(const h2*)(hb + dy * 12 + 8);
                float rowv[10] = {(float)r0[0], (float)r0[1], (float)r0[2], (float)r0[3],
                                  (float)r1[0], (float)r1[1], (float)r1[2], (float)r1[3],
                                  (float)r2[0], (float)r2[1]};
                float w0 = dwp[dy * 3], w1 = dwp[dy * 3 + 1], w2 = dwp[dy * 3 + 2];
#pragma unroll
                for (int xx = 0; xx < 8; ++xx)
                    o[xx] += w0 * rowv[xx] + w1 * rowv[xx + 1] + w2 * rowv[xx + 2];
            }
            if (ph == 0) {
                h8 qv;
#pragma unroll
                for (int xx = 0; xx < 8; ++xx) qv[xx] = (_Float16)o[xx];
                *(h8*)(qbuf + dch * 72 + drow * 8) = qv;
            } else if (ph == 1) {
                h8 kr, ko;
#pragma unroll
                for (int t2 = 0; t2 < 8; ++t2) {
                    kr[t2] = (_Float16)o[(8 - t2) & 7];
                    ko[t2] = (_Float16)o[(9 - t2) & 7];
                }
                *(h8*)(kbuf2 + dch * 136 + drow * 16) = kr;
                *(h8*)(kbuf2 + dch * 136 + drow * 16 + 8) = ko;
            } else {
                h8 vv;
#pragma unroll
                for (int xx = 0; xx < 8; ++xx) vv[xx] = (_Float16)o[xx];
                *(h8*)(vbuf + dch * 72 + drow * 8) = vv;
            }
        }
        __syncthreads();
    }

    // ---- x1o early loads (consumed into fbuf below) ----
    float xa = x1o[((size_t)(b * 16 + 2 * pr) << 16) + gpix2];
    float xb = x1o[((size_t)(b * 16 + 2 * pr + 1) << 16) + gpix2];

    // ---- stage 3: 8x8 circular convolution via fdot2 (waves 0-5) ----
    if (tid < 384) {
        int ch = tid >> 3, m = tid & 7;
        float co[8];
#pragma unroll
        for (int n = 0; n < 8; ++n) co[n] = 0.f;
#pragma unroll
        for (int i8 = 0; i8 < 8; ++i8) {
            int r = (m - i8) & 7;
            h8 q8 = *(const h8*)(qbuf + ch * 72 + i8 * 8);
            h8 e8 = *(const h8*)(kbuf2 + ch * 136 + r * 16);
#ifdef HAS_FDOT2
            h8 o8 = *(const h8*)(kbuf2 + ch * 136 + r * 16 + 8);
            h2 qp[4], ep[4], op[4];
            qp[0] = __builtin_shufflevector(q8, q8, 0, 1); qp[1] = __builtin_shufflevector(q8, q8, 2, 3);
            qp[2] = __builtin_shufflevector(q8, q8, 4, 5); qp[3] = __builtin_shufflevector(q8, q8, 6, 7);
            ep[0] = __builtin_shufflevector(e8, e8, 0, 1); ep[1] = __builtin_shufflevector(e8, e8, 2, 3);
            ep[2] = __builtin_shufflevector(e8, e8, 4, 5); ep[3] = __builtin_shufflevector(e8, e8, 6, 7);
            op[0] = __builtin_shufflevector(o8, o8, 0, 1); op[1] = __builtin_shufflevector(o8, o8, 2, 3);
            op[2] = __builtin_shufflevector(o8, o8, 4, 5); op[3] = __builtin_shufflevector(o8, o8, 6, 7);
#pragma unroll
            for (int u = 0; u < 4; ++u)
#pragma unroll
                for (int a = 0; a < 4; ++a) {
                    co[2 * u]     = __builtin_amdgcn_fdot2(qp[a], ep[(a - u) & 3], co[2 * u], false);
                    co[2 * u + 1] = __builtin_amdgcn_fdot2(qp[a], op[(a - u) & 3], co[2 * u + 1], false);
                }
#else
            float qf[8], kf[8];
#pragma unroll
            for (int j = 0; j < 8; ++j) { qf[j] = (float)q8[j]; kf[j] = (float)e8[(8 - j) & 7]; }
#pragma unroll
            for (int j = 0; j < 8; ++j)
#pragma unroll
                for (int n = 0; n < 8; ++n)
                    co[n] += qf[j] * kf[(n - j) & 7];
#endif
        }
#pragma unroll
        for (int v = 0; v < 4; ++v)
            *(h2*)(outb + ch * 72 + m * 8 + 2 * v) = (h2){(_Float16)co[2 * v], (_Float16)co[2 * v + 1]};
    }
    // fbuf x1 part (fp16)
    *(h2*)(fbuf + px2 * 72 + 2 * pr) = (h2){(_Float16)xa, (_Float16)xb};
    __syncthreads();

    // ---- stage 4a: layernorm stats ----
    {
        float s = 0.f, ss = 0.f;
#pragma unroll
        for (int cc = 0; cc < 6; ++cc) {
            float v = (float)outb[(pr * 6 + cc) * 72 + px2];
            s += v; ss += v * v;
        }
        lnp[pr * 64 + px2] = s;
        lnp[512 + pr * 64 + px2] = ss;
    }
    __syncthreads();
    if (tid < 64) {
        float s = 0.f, ss = 0.f;
#pragma unroll
        for (int g = 0; g < 8; ++g) { s += lnp[g * 64 + tid]; ss += lnp[512 + g * 64 + tid]; }
        float mu = s * (1.f / 48.f);
        float var = ss * (1.f / 48.f) - mu * mu;
        pstat[tid * 2] = mu;
        pstat[tid * 2 + 1] = rsqrtf(var + 1e-6f);
    }
    __syncthreads();

    // ---- stage 4b: sbufA[px][ch] = v * layernorm(out); zero K-pad cols 48..63 ----
    {
        float mu = pstat[lane * 2], inv = pstat[lane * 2 + 1];
        int cl0 = wave * 6;
#pragma unroll
        for (int u = 0; u < 6; ++u) {
            int cl = cl0 + u;
            float o = (float)outb[cl * 72 + lane];
            float vv = (float)vbuf[cl * 72 + lane];
            float lnv = ln_w[cl] * ((o - mu) * inv) + ln_b[cl];
            sbufA[lane * 72 + cl] = (_Float16)(vv * lnv);
        }
        *(h2*)(sbufA + px2 * 72 + 48 + 2 * pr) = (h2){(_Float16)0.f, (_Float16)0.f};
    }
    __syncthreads();

    // ---- stage 5: x2o = out_w @ sbuf + out_b (MFMA, B from global) -> fbuf[px][16+n] ----
    for (int t = wave; t < 12; t += 8) {
        int mt = t / 3, nt = t - mt * 3;
        h8 c0 = *(const h8*)(sbufA + mt * 1152 + fr);
        h8 c1 = *(const h8*)(sbufA + mt * 1152 + 32 + fr);
        h8 d0 = *(const h8*)(owlwH + nt * 1152 + fr);
        h8 d1 = *(const h8*)(owlwH + nt * 1152 + 32 + fr);
        float bias = out_b[nt * 16 + l16];
        f4 acc = {bias, bias, bias, bias};
        acc = __builtin_amdgcn_mfma_f32_16x16x32_f16(c0, d0, acc, 0, 0, 0);
        acc = __builtin_amdgcn_mfma_f32_16x16x32_f16(c1, d1, acc, 0, 0, 0);
        int n5 = nt * 16 + l16;
        int pb = mt * 16 + (lhi << 2);
#pragma unroll
        for (int r = 0; r < 4; ++r)
            fbuf[(pb + r) * 72 + 16 + n5] = (_Float16)acc[r];
    }
    __syncthreads();

    // ---- stage 6: out = last_w @ [x1;x2o] + last_b (MFMA, B from global) -> cbuf[ch][px] ----
    for (int t = wave; t < 16; t += 8) {
        int mt = t >> 2, nt = t & 3;
        h8 c0 = *(const h8*)(fbuf + mt * 1152 + fr);
        h8 c1 = *(const h8*)(fbuf + mt * 1152 + 32 + fr);
        h8 d0 = *(const h8*)(owlwH + 3456 + nt * 1152 + fr);
        h8 d1 = *(const h8*)(owlwH + 3456 + nt * 1152 + 32 + fr);
        float bias = last_b[nt * 16 + l16];
        f4 acc = {bias, bias, bias, bias};
        acc = __builtin_amdgcn_mfma_f32_16x16x32_f16(c0, d0, acc, 0, 0, 0);
        acc = __builtin_amdgcn_mfma_f32_16x16x32_f16(c1, d1, acc, 0, 0, 0);
        int ch = nt * 16 + l16;
        int pb = mt * 16 + (lhi << 2);
#pragma unroll
        for (int r = 0; r < 4; ++r)
            cbuf[ch * 72 + pb + r] = (_Float16)acc[r];
    }
    __syncthreads();

    // ---- stage 7: store ----
#pragma unroll
    for (int u = 0; u < 8; ++u) {
        int ch = pr * 8 + u;
        out[((size_t)(b * 64 + ch) << 16) + gpix2] = (float)cbuf[ch * 72 + px2];
    }
}

extern "C" void kernel_launch(void* const* d_in, const int* in_sizes, int n_in,
                              void* d_out, int out_size, void* d_ws, size_t ws_size,
                              hipStream_t stream) {
    const float* x      = (const float*)d_in[0];
    const float* dl1_w1 = (const float*)d_in[1];
    const float* dl1_b1 = (const float*)d_in[2];
    const float* dl1_w2 = (const float*)d_in[3];
    const float* dl1_b2 = (const float*)d_in[4];
    const float* dl2_w1 = (const float*)d_in[5];
    const float* dl2_b1 = (const float*)d_in[6];
    const float* dl2_w2 = (const float*)d_in[7];
    const float* dl2_b2 = (const float*)d_in[8];
    const float* hid_w  = (const float*)d_in[9];
    const float* hid_b  = (const float*)d_in[10];
    const float* dw_w   = (const float*)d_in[11];
    const float* dw_b   = (const float*)d_in[12];
    const float* ln_w   = (const float*)d_in[13];
    const float* ln_b   = (const float*)d_in[14];
    const float* out_w  = (const float*)d_in[15];
    const float* out_b  = (const float*)d_in[16];
    const float* last_w = (const float*)d_in[17];
    const float* last_b = (const float*)d_in[18];
    float* out = (float*)d_out;

    float* ws      = (float*)d_ws;
    float* pooled1 = ws;                       // 64
    float* kern1   = ws + 64;                  // 576
    float* rowsum  = ws + 1024;                // 16384
    float* kern2   = ws + 17408;               // 1600
    _Float16* hwH   = (_Float16*)(ws + 19008); // 10368 fp16
    _Float16* owlwH = (_Float16*)(ws + 24192); // 8064 fp16 -> ends 28224
    float* y1      = ws + 32768;               // 4194304
    float* x1o     = ws + 32768 + 4194304;     // 4194304

    k_prep <<<8,    256, 0, stream>>>(hid_w, out_w, last_w, hwH, owlwH);
    k_pool <<<64,   256, 0, stream>>>(x, pooled1);
    k_kern1<<<1,    256, 0, stream>>>(pooled1, dl1_w1, dl1_b1, dl1_w2, dl1_b2, kern1);
    k_dw3  <<<2048, 256, 0, stream>>>(x, kern1, y1, rowsum);
    k_kern2<<<1,    256, 0, stream>>>(rowsum, dl2_w1, dl2_b1, dl2_w2, dl2_b2, kern2);
    k_dw5  <<<2048, 256, 0, stream>>>(y1, kern2, x1o);
    k_fsas <<<4096, 512, 0, stream>>>(x, hwH, hid_b, dw_w, dw_b, ln_w, ln_b,
                                      owlwH, out_b, last_b, x1o, out);
}

// Round 6
// 176.849 us; speedup vs baseline: 4.1350x; 1.0167x over previous
//
#include <hip/hip_runtime.h>

typedef _Float16 h2 __attribute__((ext_vector_type(2)));
typedef _Float16 h4 __attribute__((ext_vector_type(4)));
typedef _Float16 h8 __attribute__((ext_vector_type(8)));
typedef float f4 __attribute__((ext_vector_type(4)));

#if defined(__has_builtin)
#if __has_builtin(__builtin_amdgcn_fdot2)
#define HAS_FDOT2 1
#endif
#endif

__device__ __forceinline__ float warpsum(float v) {
    for (int off = 32; off > 0; off >>= 1) v += __shfl_down(v, off);
    return v;
}

// element-index swizzles: XOR k-block with p-row-group; keeps 8-elem (16B) blocks contiguous
__device__ __forceinline__ int aswz(int p, int k) {       // stride 72
    return p * 72 + ((((k >> 3) ^ (p >> 3)) & 7) << 3) + (k & 7);
}
__device__ __forceinline__ int sswz(int p, int k) {       // stride 64
    return p * 64 + ((((k >> 3) ^ (p >> 3)) & 7) << 3) + (k & 7);
}

// ---------------- K_prep: fp16 weight matrices, [n][72] k-padded rows ----------------
__global__ __launch_bounds__(256) void k_prep(const float* __restrict__ hid_w,
                                              const float* __restrict__ out_w,
                                              const float* __restrict__ last_w,
                                              _Float16* __restrict__ hwH,
                                              _Float16* __restrict__ owlwH) {
    int t = blockIdx.x * 256 + threadIdx.x;
    int stride = gridDim.x * 256;
    for (int i = t; i < 10368; i += stride) {           // 144*72
        int n = i / 72, k = i - n * 72;
        hwH[i] = (k < 48) ? (_Float16)hid_w[n * 48 + k] : (_Float16)0.f;
    }
    for (int i = t; i < 3456; i += stride) {            // 48*72
        int n = i / 72, k = i - n * 72;
        owlwH[i] = (k < 48) ? (_Float16)out_w[n * 48 + k] : (_Float16)0.f;
    }
    for (int i = t; i < 4608; i += stride) {            // 64*72
        int n = i / 72, k = i - n * 72;
        owlwH[3456 + i] = (k < 64) ? (_Float16)last_w[n * 64 + k] : (_Float16)0.f;
    }
}

// ---------------- K0: pooled mean of x1 channels ----------------
__global__ __launch_bounds__(256) void k_pool(const float* __restrict__ x, float* __restrict__ pooled1) {
    int bid = blockIdx.x;            // 64 = b*16 + c
    int b = bid >> 4, c = bid & 15;
    const float* base = x + (size_t)(b * 64 + c) * 65536;
    float s = 0.f;
    for (int i = threadIdx.x; i < 16384; i += 256) {
        float4 v = ((const float4*)base)[i];
        s += v.x + v.y + v.z + v.w;
    }
    __shared__ float red[4];
    s = warpsum(s);
    if ((threadIdx.x & 63) == 0) red[threadIdx.x >> 6] = s;
    __syncthreads();
    if (threadIdx.x == 0) pooled1[bid] = (red[0] + red[1] + red[2] + red[3]) * (1.f / 65536.f);
}

// ---------------- K1: kern1 from pooled1 (tiny MLP) ----------------
__global__ __launch_bounds__(256) void k_kern1(const float* __restrict__ pooled1,
                                               const float* __restrict__ w1, const float* __restrict__ b1,
                                               const float* __restrict__ w2, const float* __restrict__ b2,
                                               float* __restrict__ kern1) {
    __shared__ float h[64];
    int t = threadIdx.x;
    if (t < 64) {
        int b = t >> 4, j = t & 15;
        float a = b1[j];
        for (int i = 0; i < 16; ++i) a += pooled1[b * 16 + i] * w1[j * 16 + i];
        h[t] = fmaxf(a, 0.f);
    }
    __syncthreads();
    for (int i = t; i < 576; i += 256) {      // 4 * 144
        int b = i / 144, o = i - b * 144;
        float a = b2[o];
        for (int j = 0; j < 16; ++j) a += h[b * 16 + j] * w2[o * 16 + j];
        kern1[i] = a;
    }
}

// ---------------- K2: dynamic depthwise 3x3 (8 rows/block, LDS-staged) + row sums ----------------
__global__ __launch_bounds__(256) void k_dw3(const float* __restrict__ x,
                                             const float* __restrict__ kern1,
                                             float* __restrict__ y1, float* __restrict__ rowsum) {
    __shared__ float tile[10][258];
    __shared__ float red[8][4];
    int bid = blockIdx.x;            // bc*32 + rb
    int rb = bid & 31, bc = bid >> 5;
    int b = bc >> 4, c = bc & 15;
    int row0 = rb << 3;
    int col = threadIdx.x;
    const float* xc = x + ((size_t)(b * 64 + c) << 16);
#pragma unroll
    for (int j = 0; j < 10; ++j) {
        int r = row0 - 1 + j;
        tile[j][col + 1] = ((unsigned)r < 256u) ? xc[(r << 8) + col] : 0.f;
    }
    if (col < 10) { tile[col][0] = 0.f; tile[col][257] = 0.f; }
    const float* k9 = kern1 + b * 144 + c * 9;
    float kk[9];
#pragma unroll
    for (int i = 0; i < 9; ++i) kk[i] = k9[i];
    __syncthreads();
#pragma unroll
    for (int j = 0; j < 8; ++j) {
        float acc = 0.f;
#pragma unroll
        for (int dy = 0; dy < 3; ++dy)
#pragma unroll
            for (int dx = 0; dx < 3; ++dx)
                acc += kk[dy * 3 + dx] * tile[j + dy][col + dx];
        y1[((size_t)bc << 16) + ((row0 + j) << 8) + col] = acc;
        float s = warpsum(acc);
        if ((col & 63) == 0) red[j][col >> 6] = s;
    }
    __syncthreads();
    if (col < 8) rowsum[bc * 256 + row0 + col] = red[col][0] + red[col][1] + red[col][2] + red[col][3];
}

// ---------------- K3: kern2 from row sums (tiny MLP) ----------------
__global__ __launch_bounds__(256) void k_kern2(const float* __restrict__ rowsum,
                                               const float* __restrict__ w1, const float* __restrict__ b1,
                                               const float* __restrict__ w2, const float* __restrict__ b2,
                                               float* __restrict__ kern2) {
    __shared__ float ps[256];
    __shared__ float p2[64];
    __shared__ float h[64];
    int t = threadIdx.x;
    {
        int pair = t >> 2, seg = t & 3;
        const float* rs = rowsum + pair * 256 + seg * 64;
        float s = 0.f;
        for (int j = 0; j < 64; ++j) s += rs[j];
        ps[t] = s;
    }
    __syncthreads();
    if (t < 64) p2[t] = (ps[t * 4] + ps[t * 4 + 1] + ps[t * 4 + 2] + ps[t * 4 + 3]) * (1.f / 65536.f);
    __syncthreads();
    if (t < 64) {
        int b = t >> 4, j = t & 15;
        float a = b1[j];
        for (int i = 0; i < 16; ++i) a += p2[b * 16 + i] * w1[j * 16 + i];
        h[t] = fmaxf(a, 0.f);
    }
    __syncthreads();
    for (int i = t; i < 1600; i += 256) {     // 4 * 400
        int b = i / 400, o = i - b * 400;
        float a = b2[o];
        for (int j = 0; j < 16; ++j) a += h[b * 16 + j] * w2[o * 16 + j];
        kern2[i] = a;
    }
}

// ---------------- K4: dynamic depthwise 5x5 (8 rows/block, LDS-staged) ----------------
__global__ __launch_bounds__(256) void k_dw5(const float* __restrict__ y1,
                                             const float* __restrict__ kern2,
                                             float* __restrict__ x1o) {
    __shared__ float tile[12][260];
    int bid = blockIdx.x;            // bc*32 + rb
    int rb = bid & 31, bc = bid >> 5;
    int b = bc >> 4, c = bc & 15;
    int row0 = rb << 3;
    int col = threadIdx.x;
    const float* yc = y1 + ((size_t)bc << 16);
#pragma unroll
    for (int j = 0; j < 12; ++j) {
        int r = row0 - 2 + j;
        tile[j][col + 2] = ((unsigned)r < 256u) ? yc[(r << 8) + col] : 0.f;
    }
    if (col < 12) { tile[col][0] = 0.f; tile[col][1] = 0.f; tile[col][258] = 0.f; tile[col][259] = 0.f; }
    const float* k25 = kern2 + b * 400 + c * 25;
    float kk[25];
#pragma unroll
    for (int i = 0; i < 25; ++i) kk[i] = k25[i];
    __syncthreads();
#pragma unroll
    for (int j = 0; j < 8; ++j) {
        float acc = 0.f;
#pragma unroll
        for (int dy = 0; dy < 5; ++dy)
#pragma unroll
            for (int dx = 0; dx < 5; ++dx)
                acc += kk[dy * 5 + dx] * tile[j + dy][col + dx];
        x1o[((size_t)bc << 16) + ((row0 + j) << 8) + col] = acc;
    }
}

// ---------------- K5: fused fsas + final conv (fp16 MFMA), one 8x8 patch per block ----------------
// LDS 39.4 KB -> 4 blocks/CU. Regions:
//  Abuf [9824] f16: halo A [128][72] swizzled (dead after frag reads). Overlays:
//     hbuf [48][120] @0, fbuf [64][72] swz @0, lnp f32[1024] @4608, outb [48][66] @6656.
//  qbuf [48][64] f16 ; kbuf2 [48][136] f16 (krev|krevrot); sbufA = kbuf2 overlay [64][64] swz.
// All weights stream global->VGPR (L2-resident). Stage-6 results store direct to global (float4).
__global__ __launch_bounds__(512, 8) void k_fsas(const float* __restrict__ x,
                                                 const _Float16* __restrict__ hwH, const float* __restrict__ hid_b,
                                                 const float* __restrict__ dw_w, const float* __restrict__ dw_b,
                                                 const float* __restrict__ ln_w, const float* __restrict__ ln_b,
                                                 const _Float16* __restrict__ owlwH, const float* __restrict__ out_b,
                                                 const float* __restrict__ last_b,
                                                 const float* __restrict__ x1o, float* __restrict__ out) {
    __shared__ __align__(16) _Float16 Abuf[9824];
    __shared__ __align__(16) _Float16 qbuf[3072];
    __shared__ __align__(16) _Float16 kbuf2[6528];
    __shared__ __align__(16) float pstat[128];

    _Float16* hbuf  = Abuf;                    // [48][120]
    _Float16* fbuf  = Abuf;                    // [64][72] swizzled
    float*    lnp   = (float*)(Abuf + 4608);   // [1024] f32
    _Float16* outb  = Abuf + 6656;             // [48][66]
    _Float16* sbufA = kbuf2;                   // [64][64] swizzled

    int tid = threadIdx.x;
    int lane = tid & 63;
    int wave = __builtin_amdgcn_readfirstlane(tid >> 6);
    int bid = blockIdx.x;
    int swz = ((bid & 7) << 9) | (bid >> 3);        // bijective XCD swizzle (4096 = 8*512)
    int b = swz >> 10;
    int rem = swz & 1023;
    int row0 = (rem >> 5) << 3, col0 = (rem & 31) << 3;

    int l16 = lane & 15, lhi = lane >> 4;
    int mb = wave * 16 + (lhi << 2);           // MFMA C-row base for stage 2
    bool st[4], vok[4];
#pragma unroll
    for (int r = 0; r < 4; ++r) {
        int m = mb + r;
        st[r] = (m < 120);
        int yv = m / 12, xv = m - yv * 12;
        vok[r] = st[r] && (xv < 10) &&
                 ((unsigned)(row0 - 1 + yv) < 256u) && ((unsigned)(col0 - 1 + xv) < 256u);
    }

    // ---- stage 1: fill A halo (p = y*12+x, cols 0..47) + K-pad zeros ----
    for (int j = tid; j < 5760; j += 512) {           // 48 * 120
        int k = j / 120, p = j - k * 120;
        int yv = p / 12, xv = p - yv * 12;
        int gy = row0 - 1 + yv, gx = col0 - 1 + xv;
        float v = 0.f;
        if (xv < 10 && (unsigned)gy < 256u && (unsigned)gx < 256u)
            v = x[((size_t)(b * 64 + 16 + k) << 16) + (gy << 8) + gx];
        Abuf[aswz(p, k)] = (_Float16)v;
    }
    for (int j = tid; j < 2048; j += 512) {           // rows 0..127, k 48..63
        int p = j >> 4, k = 48 + (j & 15);
        Abuf[aswz(p, k)] = (_Float16)0.f;
    }
    if (tid < 384) {                                  // rows 120..127, k 0..47
        int p = 120 + (tid / 48), k = tid % 48;
        Abuf[aswz(p, k)] = (_Float16)0.f;
    }
    __syncthreads();

    // A-frags into registers (row = wave*16+l16, k-blocks lhi / lhi+4)
    int arow = wave * 16 + l16;
    h8 a0 = *(const h8*)(Abuf + aswz(arow, lhi << 3));
    h8 a1 = *(const h8*)(Abuf + aswz(arow, 32 + (lhi << 3)));
    __syncthreads();   // Abuf now dead -> hbuf overlay safe

    // early x1o loads (consumed into fbuf later)
    int px2 = lane, pr = wave;
    size_t gpix2 = ((size_t)(row0 + (px2 >> 3)) << 8) + col0 + (px2 & 7);
    float xa = x1o[((size_t)(b * 16 + 2 * pr) << 16) + gpix2];
    float xb = x1o[((size_t)(b * 16 + 2 * pr + 1) << 16) + gpix2];

    int dch = tid >> 3, drow = tid & 7;   // dw/conv task mapping (tid < 384)
    h8 vreg;                              // v values stay in registers

    // ---- stage 2: hidden conv1x1 via MFMA (B from global) + dw3x3, phases q/k/v ----
#pragma unroll 1
    for (int ph = 0; ph < 3; ++ph) {
        const _Float16* wp = hwH + ph * 3456;
#pragma unroll 1
        for (int nt = 0; nt < 3; ++nt) {
            h8 b0 = *(const h8*)(wp + nt * 1152 + l16 * 72 + (lhi << 3));
            h8 b1 = *(const h8*)(wp + nt * 1152 + l16 * 72 + 32 + (lhi << 3));
            float bias = hid_b[ph * 48 + nt * 16 + l16];
            f4 acc = {bias, bias, bias, bias};
            acc = __builtin_amdgcn_mfma_f32_16x16x32_f16(a0, b0, acc, 0, 0, 0);
            acc = __builtin_amdgcn_mfma_f32_16x16x32_f16(a1, b1, acc, 0, 0, 0);
            int n_l = nt * 16 + l16;
#pragma unroll
            for (int r = 0; r < 4; ++r)
                if (st[r]) hbuf[n_l * 120 + mb + r] = vok[r] ? (_Float16)acc[r] : (_Float16)0.f;
        }
        __syncthreads();
        if (tid < 384) {
            int c = ph * 48 + dch;
            const float* dwp = dw_w + c * 9;
            float bias = dw_b[c];
            float o[8];
#pragma unroll
            for (int xx = 0; xx < 8; ++xx) o[xx] = bias;
            const _Float16* hb = hbuf + dch * 120 + drow * 12;
#pragma unroll
            for (int dy = 0; dy < 3; ++dy) {
                h4 r0 = *(const h4*)(hb + dy * 12);
                h4 r1 = *(const h4*)(hb + dy * 12 + 4);
                h2 r2 = *(const h2*)(hb + dy * 12 + 8);
                float rowv[10] = {(float)r0[0], (float)r0[1], (float)r0[2], (float)r0[3],
                                  (float)r1[0], (float)r1[1], (float)r1[2], (float)r1[3],
                                  (float)r2[0], (float)r2[1]};
                float w0 = dwp[dy * 3], w1 = dwp[dy * 3 + 1], w2 = dwp[dy * 3 + 2];
#pragma unroll
                for (int xx = 0; xx < 8; ++xx)
                    o[xx] += w0 * rowv[xx] + w1 * rowv[xx + 1] + w2 * rowv[xx + 2];
            }
            if (ph == 0) {
                h8 qv;
#pragma unroll
                for (int xx = 0; xx < 8; ++xx) qv[xx] = (_Float16)o[xx];
                *(h8*)(qbuf + dch * 64 + drow * 8) = qv;
            } else if (ph == 1) {
                h8 kr, ko;
#pragma unroll
                for (int t2 = 0; t2 < 8; ++t2) {
                    kr[t2] = (_Float16)o[(8 - t2) & 7];
                    ko[t2] = (_Float16)o[(9 - t2) & 7];
                }
                *(h8*)(kbuf2 + dch * 136 + drow * 16) = kr;
                *(h8*)(kbuf2 + dch * 136 + drow * 16 + 8) = ko;
            } else {
#pragma unroll
                for (int xx = 0; xx < 8; ++xx) vreg[xx] = (_Float16)o[xx];
            }
        }
        __syncthreads();
    }

    // fbuf x1 part (swizzled; hbuf region now dead)
    *(h2*)(fbuf + aswz(px2, 2 * pr)) = (h2){(_Float16)xa, (_Float16)xb};

    // ---- stage 3: 8x8 circular conv via fdot2; co stays in registers ----
    float co[8];
    if (tid < 384) {
        int ch = dch, m = drow;
#pragma unroll
        for (int n = 0; n < 8; ++n) co[n] = 0.f;
#pragma unroll
        for (int i8 = 0; i8 < 8; ++i8) {
            int r = (m - i8) & 7;
            h8 q8 = *(const h8*)(qbuf + ch * 64 + i8 * 8);
            h8 e8 = *(const h8*)(kbuf2 + ch * 136 + r * 16);
#ifdef HAS_FDOT2
            h8 o8 = *(const h8*)(kbuf2 + ch * 136 + r * 16 + 8);
            h2 qp[4], ep[4], op[4];
            qp[0] = __builtin_shufflevector(q8, q8, 0, 1); qp[1] = __builtin_shufflevector(q8, q8, 2, 3);
            qp[2] = __builtin_shufflevector(q8, q8, 4, 5); qp[3] = __builtin_shufflevector(q8, q8, 6, 7);
            ep[0] = __builtin_shufflevector(e8, e8, 0, 1); ep[1] = __builtin_shufflevector(e8, e8, 2, 3);
            ep[2] = __builtin_shufflevector(e8, e8, 4, 5); ep[3] = __builtin_shufflevector(e8, e8, 6, 7);
            op[0] = __builtin_shufflevector(o8, o8, 0, 1); op[1] = __builtin_shufflevector(o8, o8, 2, 3);
            op[2] = __builtin_shufflevector(o8, o8, 4, 5); op[3] = __builtin_shufflevector(o8, o8, 6, 7);
#pragma unroll
            for (int u = 0; u < 4; ++u)
#pragma unroll
                for (int a = 0; a < 4; ++a) {
                    co[2 * u]     = __builtin_amdgcn_fdot2(qp[a], ep[(a - u) & 3], co[2 * u], false);
                    co[2 * u + 1] = __builtin_amdgcn_fdot2(qp[a], op[(a - u) & 3], co[2 * u + 1], false);
                }
#else
            float qf[8], kf[8];
#pragma unroll
            for (int j = 0; j < 8; ++j) { qf[j] = (float)q8[j]; kf[j] = (float)e8[(8 - j) & 7]; }
#pragma unroll
            for (int j = 0; j < 8; ++j)
#pragma unroll
                for (int n = 0; n < 8; ++n)
                    co[n] += qf[j] * kf[(n - j) & 7];
#endif
        }
        // store to outb for LN stats only (values kept in co[])
#pragma unroll
        for (int v = 0; v < 4; ++v)
            *(h2*)(outb + dch * 66 + drow * 8 + 2 * v) = (h2){(_Float16)co[2 * v], (_Float16)co[2 * v + 1]};
    }
    __syncthreads();

    // ---- stage 4a: layernorm stats (512 threads over outb) ----
    {
        int px = tid & 63, g = tid >> 6;     // 8 groups x 6 channels
        float s = 0.f, ss = 0.f;
#pragma unroll
        for (int cc = 0; cc < 6; ++cc) {
            float v = (float)outb[(g * 6 + cc) * 66 + px];
            s += v; ss += v * v;
        }
        lnp[g * 64 + px] = s;
        lnp[512 + g * 64 + px] = ss;
    }
    __syncthreads();
    if (tid < 64) {
        float s = 0.f, ss = 0.f;
#pragma unroll
        for (int g = 0; g < 8; ++g) { s += lnp[g * 64 + tid]; ss += lnp[512 + g * 64 + tid]; }
        float mu = s * (1.f / 48.f);
        float var = ss * (1.f / 48.f) - mu * mu;
        pstat[tid * 2] = mu;
        pstat[tid * 2 + 1] = rsqrtf(var + 1e-6f);
    }
    __syncthreads();

    // ---- stage 4b: sbufA[px][ch] = v * layernorm(out) from registers; pad cols 48..63 ----
    if (tid < 384) {
        int ch = dch, m = drow;
        float lw = ln_w[ch], lb = ln_b[ch];
        const float* ps = pstat + m * 16;
#pragma unroll
        for (int n = 0; n < 8; ++n) {
            float mu = ps[2 * n], inv = ps[2 * n + 1];
            float lnv = lw * ((co[n] - mu) * inv) + lb;
            sbufA[sswz(m * 8 + n, ch)] = (_Float16)((float)vreg[n] * lnv);
        }
    }
    *(h2*)(sbufA + sswz(px2, 48 + ((tid >> 6) << 1))) = (h2){(_Float16)0.f, (_Float16)0.f};
    __syncthreads();

    // ---- stage 5: x2o = out_w @ sbuf + out_b (MFMA) -> fbuf[px][16+n] swizzled ----
    for (int t = wave; t < 12; t += 8) {
        int mt = t / 3, nt = t - mt * 3;
        int row5 = mt * 16 + l16;
        h8 c0 = *(const h8*)(sbufA + sswz(row5, lhi << 3));
        h8 c1 = *(const h8*)(sbufA + sswz(row5, 32 + (lhi << 3)));
        h8 d0 = *(const h8*)(owlwH + nt * 1152 + l16 * 72 + (lhi << 3));
        h8 d1 = *(const h8*)(owlwH + nt * 1152 + l16 * 72 + 32 + (lhi << 3));
        float bias = out_b[nt * 16 + l16];
        f4 acc = {bias, bias, bias, bias};
        acc = __builtin_amdgcn_mfma_f32_16x16x32_f16(c0, d0, acc, 0, 0, 0);
        acc = __builtin_amdgcn_mfma_f32_16x16x32_f16(c1, d1, acc, 0, 0, 0);
        int n5 = nt * 16 + l16;
        int pb = mt * 16 + (lhi << 2);
#pragma unroll
        for (int r = 0; r < 4; ++r)
            fbuf[aswz(pb + r, 16 + n5)] = (_Float16)acc[r];
    }
    __syncthreads();

    // ---- stage 6: out = last_w @ [x1;x2o] + last_b (MFMA) -> direct global float4 ----
    for (int t = wave; t < 16; t += 8) {
        int mt = t >> 2, nt = t & 3;
        int row6 = mt * 16 + l16;
        h8 c0 = *(const h8*)(fbuf + aswz(row6, lhi << 3));
        h8 c1 = *(const h8*)(fbuf + aswz(row6, 32 + (lhi << 3)));
        h8 d0 = *(const h8*)(owlwH + 3456 + nt * 1152 + l16 * 72 + (lhi << 3));
        h8 d1 = *(const h8*)(owlwH + 3456 + nt * 1152 + l16 * 72 + 32 + (lhi << 3));
        float bias = last_b[nt * 16 + l16];
        f4 acc = {bias, bias, bias, bias};
        acc = __builtin_amdgcn_mfma_f32_16x16x32_f16(c0, d0, acc, 0, 0, 0);
        acc = __builtin_amdgcn_mfma_f32_16x16x32_f16(c1, d1, acc, 0, 0, 0);
        int ch = nt * 16 + l16;
        int px0 = mt * 16 + (lhi << 2);
        float4 val = {acc[0], acc[1], acc[2], acc[3]};
        *(float4*)(out + ((size_t)(b * 64 + ch) << 16) + ((size_t)(row0 + (px0 >> 3)) << 8) + col0 + (px0 & 7)) = val;
    }
}

extern "C" void kernel_launch(void* const* d_in, const int* in_sizes, int n_in,
                              void* d_out, int out_size, void* d_ws, size_t ws_size,
                              hipStream_t stream) {
    const float* x      = (const float*)d_in[0];
    const float* dl1_w1 = (const float*)d_in[1];
    const float* dl1_b1 = (const float*)d_in[2];
    const float* dl1_w2 = (const float*)d_in[3];
    const float* dl1_b2 = (const float*)d_in[4];
    const float* dl2_w1 = (const float*)d_in[5];
    const float* dl2_b1 = (const float*)d_in[6];
    const float* dl2_w2 = (const float*)d_in[7];
    const float* dl2_b2 = (const float*)d_in[8];
    const float* hid_w  = (const float*)d_in[9];
    const float* hid_b  = (const float*)d_in[10];
    const float* dw_w   = (const float*)d_in[11];
    const float* dw_b   = (const float*)d_in[12];
    const float* ln_w   = (const float*)d_in[13];
    const float* ln_b   = (const float*)d_in[14];
    const float* out_w  = (const float*)d_in[15];
    const float* out_b  = (const float*)d_in[16];
    const float* last_w = (const float*)d_in[17];
    const float* last_b = (const float*)d_in[18];
    float* out = (float*)d_out;

    float* ws      = (float*)d_ws;
    float* pooled1 = ws;                       // 64
    float* kern1   = ws + 64;                  // 576
    float* rowsum  = ws + 1024;                // 16384
    float* kern2   = ws + 17408;               // 1600
    _Float16* hwH   = (_Float16*)(ws + 19008); // 10368 fp16
    _Float16* owlwH = (_Float16*)(ws + 24192); // 8064 fp16 -> ends 28224
    float* y1      = ws + 32768;               // 4194304
    float* x1o     = ws + 32768 + 4194304;     // 4194304

    k_prep <<<8,    256, 0, stream>>>(hid_w, out_w, last_w, hwH, owlwH);
    k_pool <<<64,   256, 0, stream>>>(x, pooled1);
    k_kern1<<<1,    256, 0, stream>>>(pooled1, dl1_w1, dl1_b1, dl1_w2, dl1_b2, kern1);
    k_dw3  <<<2048, 256, 0, stream>>>(x, kern1, y1, rowsum);
    k_kern2<<<1,    256, 0, stream>>>(rowsum, dl2_w1, dl2_b1, dl2_w2, dl2_b2, kern2);
    k_dw5  <<<2048, 256, 0, stream>>>(y1, kern2, x1o);
    k_fsas <<<4096, 512, 0, stream>>>(x, hwH, hid_b, dw_w, dw_b, ln_w, ln_b,
                                      owlwH, out_b, last_b, x1o, out);
}

// Round 7
// 167.056 us; speedup vs baseline: 4.3774x; 1.0586x over previous
//
#include <hip/hip_runtime.h>

typedef _Float16 h2 __attribute__((ext_vector_type(2)));
typedef _Float16 h4 __attribute__((ext_vector_type(4)));
typedef _Float16 h8 __attribute__((ext_vector_type(8)));
typedef float f4 __attribute__((ext_vector_type(4)));

#if defined(__has_builtin)
#if __has_builtin(__builtin_amdgcn_fdot2)
#define HAS_FDOT2 1
#endif
#endif

__device__ __forceinline__ float warpsum(float v) {
    for (int off = 32; off > 0; off >>= 1) v += __shfl_down(v, off);
    return v;
}

// element-index swizzles: XOR k-block with p-row-group; keeps 8-elem (16B) blocks contiguous
__device__ __forceinline__ int aswz(int p, int k) {       // stride 72
    return p * 72 + ((((k >> 3) ^ (p >> 3)) & 7) << 3) + (k & 7);
}
__device__ __forceinline__ int sswz(int p, int k) {       // stride 64
    return p * 64 + ((((k >> 3) ^ (p >> 3)) & 7) << 3) + (k & 7);
}

// ---------------- K_prep: fp16 weight matrices, [n][72] k-padded rows ----------------
__global__ __launch_bounds__(256) void k_prep(const float* __restrict__ hid_w,
                                              const float* __restrict__ out_w,
                                              const float* __restrict__ last_w,
                                              _Float16* __restrict__ hwH,
                                              _Float16* __restrict__ owlwH) {
    int t = blockIdx.x * 256 + threadIdx.x;
    int stride = gridDim.x * 256;
    for (int i = t; i < 10368; i += stride) {           // 144*72
        int n = i / 72, k = i - n * 72;
        hwH[i] = (k < 48) ? (_Float16)hid_w[n * 48 + k] : (_Float16)0.f;
    }
    for (int i = t; i < 3456; i += stride) {            // 48*72
        int n = i / 72, k = i - n * 72;
        owlwH[i] = (k < 48) ? (_Float16)out_w[n * 48 + k] : (_Float16)0.f;
    }
    for (int i = t; i < 4608; i += stride) {            // 64*72
        int n = i / 72, k = i - n * 72;
        owlwH[3456 + i] = (k < 64) ? (_Float16)last_w[n * 64 + k] : (_Float16)0.f;
    }
}

// ---------------- K0: pooled mean of x1 channels ----------------
__global__ __launch_bounds__(256) void k_pool(const float* __restrict__ x, float* __restrict__ pooled1) {
    int bid = blockIdx.x;            // 64 = b*16 + c
    int b = bid >> 4, c = bid & 15;
    const float* base = x + (size_t)(b * 64 + c) * 65536;
    float s = 0.f;
    for (int i = threadIdx.x; i < 16384; i += 256) {
        float4 v = ((const float4*)base)[i];
        s += v.x + v.y + v.z + v.w;
    }
    __shared__ float red[4];
    s = warpsum(s);
    if ((threadIdx.x & 63) == 0) red[threadIdx.x >> 6] = s;
    __syncthreads();
    if (threadIdx.x == 0) pooled1[bid] = (red[0] + red[1] + red[2] + red[3]) * (1.f / 65536.f);
}

// ---------------- K1: kern1 from pooled1 (tiny MLP) ----------------
__global__ __launch_bounds__(256) void k_kern1(const float* __restrict__ pooled1,
                                               const float* __restrict__ w1, const float* __restrict__ b1,
                                               const float* __restrict__ w2, const float* __restrict__ b2,
                                               float* __restrict__ kern1) {
    __shared__ float h[64];
    int t = threadIdx.x;
    if (t < 64) {
        int b = t >> 4, j = t & 15;
        float a = b1[j];
        for (int i = 0; i < 16; ++i) a += pooled1[b * 16 + i] * w1[j * 16 + i];
        h[t] = fmaxf(a, 0.f);
    }
    __syncthreads();
    for (int i = t; i < 576; i += 256) {      // 4 * 144
        int b = i / 144, o = i - b * 144;
        float a = b2[o];
        for (int j = 0; j < 16; ++j) a += h[b * 16 + j] * w2[o * 16 + j];
        kern1[i] = a;
    }
}

// ---------------- K2: dynamic depthwise 3x3 (8 rows/block, LDS-staged) + row sums ----------------
__global__ __launch_bounds__(256) void k_dw3(const float* __restrict__ x,
                                             const float* __restrict__ kern1,
                                             float* __restrict__ y1, float* __restrict__ rowsum) {
    __shared__ float tile[10][258];
    __shared__ float red[8][4];
    int bid = blockIdx.x;            // bc*32 + rb
    int rb = bid & 31, bc = bid >> 5;
    int b = bc >> 4, c = bc & 15;
    int row0 = rb << 3;
    int col = threadIdx.x;
    const float* xc = x + ((size_t)(b * 64 + c) << 16);
#pragma unroll
    for (int j = 0; j < 10; ++j) {
        int r = row0 - 1 + j;
        tile[j][col + 1] = ((unsigned)r < 256u) ? xc[(r << 8) + col] : 0.f;
    }
    if (col < 10) { tile[col][0] = 0.f; tile[col][257] = 0.f; }
    const float* k9 = kern1 + b * 144 + c * 9;
    float kk[9];
#pragma unroll
    for (int i = 0; i < 9; ++i) kk[i] = k9[i];
    __syncthreads();
#pragma unroll
    for (int j = 0; j < 8; ++j) {
        float acc = 0.f;
#pragma unroll
        for (int dy = 0; dy < 3; ++dy)
#pragma unroll
            for (int dx = 0; dx < 3; ++dx)
                acc += kk[dy * 3 + dx] * tile[j + dy][col + dx];
        y1[((size_t)bc << 16) + ((row0 + j) << 8) + col] = acc;
        float s = warpsum(acc);
        if ((col & 63) == 0) red[j][col >> 6] = s;
    }
    __syncthreads();
    if (col < 8) rowsum[bc * 256 + row0 + col] = red[col][0] + red[col][1] + red[col][2] + red[col][3];
}

// ---------------- K3: kern2 from row sums (tiny MLP) ----------------
__global__ __launch_bounds__(256) void k_kern2(const float* __restrict__ rowsum,
                                               const float* __restrict__ w1, const float* __restrict__ b1,
                                               const float* __restrict__ w2, const float* __restrict__ b2,
                                               float* __restrict__ kern2) {
    __shared__ float ps[256];
    __shared__ float p2[64];
    __shared__ float h[64];
    int t = threadIdx.x;
    {
        int pair = t >> 2, seg = t & 3;
        const float* rs = rowsum + pair * 256 + seg * 64;
        float s = 0.f;
        for (int j = 0; j < 64; ++j) s += rs[j];
        ps[t] = s;
    }
    __syncthreads();
    if (t < 64) p2[t] = (ps[t * 4] + ps[t * 4 + 1] + ps[t * 4 + 2] + ps[t * 4 + 3]) * (1.f / 65536.f);
    __syncthreads();
    if (t < 64) {
        int b = t >> 4, j = t & 15;
        float a = b1[j];
        for (int i = 0; i < 16; ++i) a += p2[b * 16 + i] * w1[j * 16 + i];
        h[t] = fmaxf(a, 0.f);
    }
    __syncthreads();
    for (int i = t; i < 1600; i += 256) {     // 4 * 400
        int b = i / 400, o = i - b * 400;
        float a = b2[o];
        for (int j = 0; j < 16; ++j) a += h[b * 16 + j] * w2[o * 16 + j];
        kern2[i] = a;
    }
}

// ---------------- K4: dynamic depthwise 5x5 (8 rows/block, LDS-staged) ----------------
__global__ __launch_bounds__(256) void k_dw5(const float* __restrict__ y1,
                                             const float* __restrict__ kern2,
                                             float* __restrict__ x1o) {
    __shared__ float tile[12][260];
    int bid = blockIdx.x;            // bc*32 + rb
    int rb = bid & 31, bc = bid >> 5;
    int b = bc >> 4, c = bc & 15;
    int row0 = rb << 3;
    int col = threadIdx.x;
    const float* yc = y1 + ((size_t)bc << 16);
#pragma unroll
    for (int j = 0; j < 12; ++j) {
        int r = row0 - 2 + j;
        tile[j][col + 2] = ((unsigned)r < 256u) ? yc[(r << 8) + col] : 0.f;
    }
    if (col < 12) { tile[col][0] = 0.f; tile[col][1] = 0.f; tile[col][258] = 0.f; tile[col][259] = 0.f; }
    const float* k25 = kern2 + b * 400 + c * 25;
    float kk[25];
#pragma unroll
    for (int i = 0; i < 25; ++i) kk[i] = k25[i];
    __syncthreads();
#pragma unroll
    for (int j = 0; j < 8; ++j) {
        float acc = 0.f;
#pragma unroll
        for (int dy = 0; dy < 5; ++dy)
#pragma unroll
            for (int dx = 0; dx < 5; ++dx)
                acc += kk[dy * 5 + dx] * tile[j + dy][col + dx];
        x1o[((size_t)bc << 16) + ((row0 + j) << 8) + col] = acc;
    }
}

// ---------------- K5: fused fsas + final conv (fp16 MFMA), single merged phase ----------------
// LDS 62.3 KB (2 blocks/CU). Sbig [17856] f16:
//   A [128][72] swz (dead after frag read) -> hbuf [144][124] overlay.
//   After dw: fbuf [64][72] swz @0, lnp f32[1024] @4608, outb [48][66] @6656.
// vbuf [48][72]; qbuf [48][64]; kbuf2 [48][136] -> sbufA [64][64] swz overlay; pstat f32[128].
// All 144 hidden channels in ONE MFMA burst; hw weights + biases preloaded to VGPR
// before the fill barrier (L2-resident; explicit preload because barriers fence loads).
__global__ __launch_bounds__(512, 4) void k_fsas(const float* __restrict__ x,
                                                 const _Float16* __restrict__ hwH, const float* __restrict__ hid_b,
                                                 const float* __restrict__ dw_w, const float* __restrict__ dw_b,
                                                 const float* __restrict__ ln_w, const float* __restrict__ ln_b,
                                                 const _Float16* __restrict__ owlwH, const float* __restrict__ out_b,
                                                 const float* __restrict__ last_b,
                                                 const float* __restrict__ x1o, float* __restrict__ out) {
    __shared__ __align__(16) _Float16 Sbig[17856];
    __shared__ __align__(16) _Float16 vbuf[3456];
    __shared__ __align__(16) _Float16 qbuf[3072];
    __shared__ __align__(16) _Float16 kbuf2[6528];
    __shared__ __align__(16) float pstat[128];

    _Float16* Abuf  = Sbig;                    // [128][72] swz
    _Float16* hbuf  = Sbig;                    // [144][124]
    _Float16* fbuf  = Sbig;                    // [64][72] swz
    float*    lnp   = (float*)(Sbig + 4608);   // f32[1024]
    _Float16* outb  = Sbig + 6656;             // [48][66]
    _Float16* sbufA = kbuf2;                   // [64][64] swz

    int tid = threadIdx.x;
    int lane = tid & 63;
    int wave = __builtin_amdgcn_readfirstlane(tid >> 6);
    int bid = blockIdx.x;
    int swz = ((bid & 7) << 9) | (bid >> 3);        // bijective XCD swizzle (4096 = 8*512)
    int b = swz >> 10;
    int rem = swz & 1023;
    int row0 = (rem >> 5) << 3, col0 = (rem & 31) << 3;

    int l16 = lane & 15, lhi = lane >> 4;
    int mb = wave * 16 + (lhi << 2);           // MFMA C-row base (mt = wave)
    bool st[4], vok[4];
#pragma unroll
    for (int r = 0; r < 4; ++r) {
        int m = mb + r;
        st[r] = (m < 120);
        int yv = m / 12, xv = m - yv * 12;
        vok[r] = st[r] && (xv < 10) &&
                 ((unsigned)(row0 - 1 + yv) < 256u) && ((unsigned)(col0 - 1 + xv) < 256u);
    }

    // ---- preload: hidden weights (18 x h8) + biases for this wave's M-tile ----
    h8 wb0[9], wb1[9];
    float biasr[9];
#pragma unroll
    for (int nt = 0; nt < 9; ++nt) {
        const _Float16* wr = hwH + (nt * 16 + l16) * 72 + (lhi << 3);
        wb0[nt] = *(const h8*)(wr);
        wb1[nt] = *(const h8*)(wr + 32);
        biasr[nt] = hid_b[nt * 16 + l16];
    }
    // x1o preload for waves 6-7 (consumed into fbuf after dw)
    float xr[8];
    int fpx = lane, fgrp = wave - 6;
    if (wave >= 6) {
        size_t gp = ((size_t)(row0 + (fpx >> 3)) << 8) + col0 + (fpx & 7);
#pragma unroll
        for (int j = 0; j < 8; ++j)
            xr[j] = x1o[((size_t)(b * 16 + fgrp * 8 + j) << 16) + gp];
    }

    // ---- stage 1: fill A halo (p = y*12+x, k 0..47) + zero pads ----
    if (tid < 480) {
        int k = tid / 10, y = tid - (tid / 10) * 10;
        int gy = row0 - 1 + y;
        bool rowok = (unsigned)gy < 256u;
        const float* xk = x + ((size_t)(b * 64 + 16 + k) << 16) + ((size_t)(gy & 255) << 8);
#pragma unroll
        for (int xx = 0; xx < 10; ++xx) {
            int gx = col0 - 1 + xx;
            float v = (rowok && (unsigned)gx < 256u) ? xk[gx] : 0.f;
            Abuf[aswz(y * 12 + xx, k)] = (_Float16)v;
        }
        Abuf[aswz(y * 12 + 10, k)] = (_Float16)0.f;
        Abuf[aswz(y * 12 + 11, k)] = (_Float16)0.f;
    }
    if (tid < 256) {                    // k 48..63, all 128 rows
        int p = tid >> 1, kb = 48 + ((tid & 1) << 3);
        *(h8*)(Abuf + aswz(p, kb)) = (h8)(_Float16)0.f;
    }
    if (tid < 48) {                     // rows 120..127, k 0..47
        int p = 120 + tid / 6, kb = (tid % 6) << 3;
        *(h8*)(Abuf + aswz(p, kb)) = (h8)(_Float16)0.f;
    }
    __syncthreads();

    // ---- a-frags for this wave's M-tile ----
    int arow = wave * 16 + l16;
    h8 a0 = *(const h8*)(Abuf + aswz(arow, lhi << 3));
    h8 a1 = *(const h8*)(Abuf + aswz(arow, 32 + (lhi << 3)));
    __syncthreads();   // Abuf dead -> hbuf overlay safe

    // ---- stage 2: all 144 hidden channels, one MFMA burst ----
#pragma unroll
    for (int nt = 0; nt < 9; ++nt) {
        float bias = biasr[nt];
        f4 acc = {bias, bias, bias, bias};
        acc = __builtin_amdgcn_mfma_f32_16x16x32_f16(a0, wb0[nt], acc, 0, 0, 0);
        acc = __builtin_amdgcn_mfma_f32_16x16x32_f16(a1, wb1[nt], acc, 0, 0, 0);
        int n_l = nt * 16 + l16;
#pragma unroll
        for (int r = 0; r < 4; ++r)
            if (st[r]) hbuf[n_l * 124 + mb + r] = vok[r] ? (_Float16)acc[r] : (_Float16)0.f;
    }
    __syncthreads();

    // ---- stage 3: depthwise 3x3, all 144 channels (1152 row-tasks / 512 threads) ----
    {
        int row = tid & 7;
        auto dw_task = [&](int ch) {
            const float* dwp = dw_w + ch * 9;
            float o[8];
            float bias = dw_b[ch];
#pragma unroll
            for (int xx = 0; xx < 8; ++xx) o[xx] = bias;
            const _Float16* hb = hbuf + ch * 124 + row * 12;
#pragma unroll
            for (int dy = 0; dy < 3; ++dy) {
                h4 r0 = *(const h4*)(hb + dy * 12);
                h4 r1 = *(const h4*)(hb + dy * 12 + 4);
                h2 r2 = *(const h2*)(hb + dy * 12 + 8);
                float rowv[10] = {(float)r0[0], (float)r0[1], (float)r0[2], (float)r0[3],
                                  (float)r1[0], (float)r1[1], (float)r1[2], (float)r1[3],
                                  (float)r2[0], (float)r2[1]};
                float w0 = dwp[dy * 3], w1 = dwp[dy * 3 + 1], w2 = dwp[dy * 3 + 2];
#pragma unroll
                for (int xx = 0; xx < 8; ++xx)
                    o[xx] += w0 * rowv[xx] + w1 * rowv[xx + 1] + w2 * rowv[xx + 2];
            }
            if (ch < 48) {
                h8 qv;
#pragma unroll
                for (int xx = 0; xx < 8; ++xx) qv[xx] = (_Float16)o[xx];
                *(h8*)(qbuf + ch * 64 + row * 8) = qv;
            } else if (ch < 96) {
                int kc = ch - 48;
                h8 kr, ko;
#pragma unroll
                for (int t2 = 0; t2 < 8; ++t2) {
                    kr[t2] = (_Float16)o[(8 - t2) & 7];
                    ko[t2] = (_Float16)o[(9 - t2) & 7];
                }
                *(h8*)(kbuf2 + kc * 136 + row * 16) = kr;
                *(h8*)(kbuf2 + kc * 136 + row * 16 + 8) = ko;
            } else {
                int vc = ch - 96;
                h8 vv;
#pragma unroll
                for (int xx = 0; xx < 8; ++xx) vv[xx] = (_Float16)o[xx];
                *(h8*)(vbuf + vc * 72 + row * 8) = vv;
            }
        };
        dw_task(tid >> 3);
        dw_task(64 + (tid >> 3));
        if (tid < 128) dw_task(128 + (tid >> 3));
    }
    __syncthreads();

    // ---- stage 4: circular conv (waves 0-5) / fbuf x1 writes (waves 6-7) ----
    float co[8];
    int dch = tid >> 3, drow = tid & 7;
    if (tid < 384) {
        int ch = dch, m = drow;
#pragma unroll
        for (int n = 0; n < 8; ++n) co[n] = 0.f;
#pragma unroll
        for (int i8 = 0; i8 < 8; ++i8) {
            int r = (m - i8) & 7;
            h8 q8 = *(const h8*)(qbuf + ch * 64 + i8 * 8);
            h8 e8 = *(const h8*)(kbuf2 + ch * 136 + r * 16);
#ifdef HAS_FDOT2
            h8 o8 = *(const h8*)(kbuf2 + ch * 136 + r * 16 + 8);
            h2 qp[4], ep[4], op[4];
            qp[0] = __builtin_shufflevector(q8, q8, 0, 1); qp[1] = __builtin_shufflevector(q8, q8, 2, 3);
            qp[2] = __builtin_shufflevector(q8, q8, 4, 5); qp[3] = __builtin_shufflevector(q8, q8, 6, 7);
            ep[0] = __builtin_shufflevector(e8, e8, 0, 1); ep[1] = __builtin_shufflevector(e8, e8, 2, 3);
            ep[2] = __builtin_shufflevector(e8, e8, 4, 5); ep[3] = __builtin_shufflevector(e8, e8, 6, 7);
            op[0] = __builtin_shufflevector(o8, o8, 0, 1); op[1] = __builtin_shufflevector(o8, o8, 2, 3);
            op[2] = __builtin_shufflevector(o8, o8, 4, 5); op[3] = __builtin_shufflevector(o8, o8, 6, 7);
#pragma unroll
            for (int u = 0; u < 4; ++u)
#pragma unroll
                for (int a = 0; a < 4; ++a) {
                    co[2 * u]     = __builtin_amdgcn_fdot2(qp[a], ep[(a - u) & 3], co[2 * u], false);
                    co[2 * u + 1] = __builtin_amdgcn_fdot2(qp[a], op[(a - u) & 3], co[2 * u + 1], false);
                }
#else
            float qf[8], kf[8];
#pragma unroll
            for (int j = 0; j < 8; ++j) { qf[j] = (float)q8[j]; kf[j] = (float)e8[(8 - j) & 7]; }
#pragma unroll
            for (int j = 0; j < 8; ++j)
#pragma unroll
                for (int n = 0; n < 8; ++n)
                    co[n] += qf[j] * kf[(n - j) & 7];
#endif
        }
#pragma unroll
        for (int v = 0; v < 4; ++v)
            *(h2*)(outb + dch * 66 + drow * 8 + 2 * v) = (h2){(_Float16)co[2 * v], (_Float16)co[2 * v + 1]};
    } else {
        h8 fv;
#pragma unroll
        for (int j = 0; j < 8; ++j) fv[j] = (_Float16)xr[j];
        *(h8*)(fbuf + aswz(fpx, fgrp * 8)) = fv;
    }
    __syncthreads();

    // ---- stage 5a: layernorm stats ----
    {
        int px = tid & 63, g = tid >> 6;
        float s = 0.f, ss = 0.f;
#pragma unroll
        for (int cc = 0; cc < 6; ++cc) {
            float v = (float)outb[(g * 6 + cc) * 66 + px];
            s += v; ss += v * v;
        }
        lnp[g * 64 + px] = s;
        lnp[512 + g * 64 + px] = ss;
    }
    __syncthreads();
    if (tid < 64) {
        float s = 0.f, ss = 0.f;
#pragma unroll
        for (int g = 0; g < 8; ++g) { s += lnp[g * 64 + tid]; ss += lnp[512 + g * 64 + tid]; }
        float mu = s * (1.f / 48.f);
        float var = ss * (1.f / 48.f) - mu * mu;
        pstat[tid * 2] = mu;
        pstat[tid * 2 + 1] = rsqrtf(var + 1e-6f);
    }
    __syncthreads();

    // ---- stage 5b: sbufA[px][ch] = v * layernorm(out); pad cols 48..63 ----
    if (tid < 384) {
        int ch = dch, m = drow;
        float lw = ln_w[ch], lb = ln_b[ch];
        h8 vv = *(const h8*)(vbuf + ch * 72 + m * 8);
        const float* ps = pstat + m * 16;
#pragma unroll
        for (int n = 0; n < 8; ++n) {
            float mu = ps[2 * n], inv = ps[2 * n + 1];
            float lnv = lw * ((co[n] - mu) * inv) + lb;
            sbufA[sswz(m * 8 + n, ch)] = (_Float16)((float)vv[n] * lnv);
        }
    }
    *(h2*)(sbufA + sswz(lane, 48 + (wave << 1))) = (h2){(_Float16)0.f, (_Float16)0.f};
    __syncthreads();

    // ---- stage 6: x2o = out_w @ sbuf + out_b -> fbuf[px][16+n] ----
    for (int t = wave; t < 12; t += 8) {
        int mt = t / 3, nt = t - mt * 3;
        int row5 = mt * 16 + l16;
        h8 c0 = *(const h8*)(sbufA + sswz(row5, lhi << 3));
        h8 c1 = *(const h8*)(sbufA + sswz(row5, 32 + (lhi << 3)));
        h8 d0 = *(const h8*)(owlwH + nt * 1152 + l16 * 72 + (lhi << 3));
        h8 d1 = *(const h8*)(owlwH + nt * 1152 + l16 * 72 + 32 + (lhi << 3));
        float bias = out_b[nt * 16 + l16];
        f4 acc = {bias, bias, bias, bias};
        acc = __builtin_amdgcn_mfma_f32_16x16x32_f16(c0, d0, acc, 0, 0, 0);
        acc = __builtin_amdgcn_mfma_f32_16x16x32_f16(c1, d1, acc, 0, 0, 0);
        int n5 = nt * 16 + l16;
        int pb = mt * 16 + (lhi << 2);
#pragma unroll
        for (int r = 0; r < 4; ++r)
            fbuf[aswz(pb + r, 16 + n5)] = (_Float16)acc[r];
    }
    __syncthreads();

    // ---- stage 7: out = last_w @ [x1;x2o] + last_b -> direct global float4 ----
    for (int t = wave; t < 16; t += 8) {
        int mt = t >> 2, nt = t & 3;
        int row6 = mt * 16 + l16;
        h8 c0 = *(const h8*)(fbuf + aswz(row6, lhi << 3));
        h8 c1 = *(const h8*)(fbuf + aswz(row6, 32 + (lhi << 3)));
        h8 d0 = *(const h8*)(owlwH + 3456 + nt * 1152 + l16 * 72 + (lhi << 3));
        h8 d1 = *(const h8*)(owlwH + 3456 + nt * 1152 + l16 * 72 + 32 + (lhi << 3));
        float bias = last_b[nt * 16 + l16];
        f4 acc = {bias, bias, bias, bias};
        acc = __builtin_amdgcn_mfma_f32_16x16x32_f16(c0, d0, acc, 0, 0, 0);
        acc = __builtin_amdgcn_mfma_f32_16x16x32_f16(c1, d1, acc, 0, 0, 0);
        int ch = nt * 16 + l16;
        int px0 = mt * 16 + (lhi << 2);
        float4 val = {acc[0], acc[1], acc[2], acc[3]};
        *(float4*)(out + ((size_t)(b * 64 + ch) << 16) + ((size_t)(row0 + (px0 >> 3)) << 8) + col0 + (px0 & 7)) = val;
    }
}

extern "C" void kernel_launch(void* const* d_in, const int* in_sizes, int n_in,
                              void* d_out, int out_size, void* d_ws, size_t ws_size,
                              hipStream_t stream) {
    const float* x      = (const float*)d_in[0];
    const float* dl1_w1 = (const float*)d_in[1];
    const float* dl1_b1 = (const float*)d_in[2];
    const float* dl1_w2 = (const float*)d_in[3];
    const float* dl1_b2 = (const float*)d_in[4];
    const float* dl2_w1 = (const float*)d_in[5];
    const float* dl2_b1 = (const float*)d_in[6];
    const float* dl2_w2 = (const float*)d_in[7];
    const float* dl2_b2 = (const float*)d_in[8];
    const float* hid_w  = (const float*)d_in[9];
    const float* hid_b  = (const float*)d_in[10];
    const float* dw_w   = (const float*)d_in[11];
    const float* dw_b   = (const float*)d_in[12];
    const float* ln_w   = (const float*)d_in[13];
    const float* ln_b   = (const float*)d_in[14];
    const float* out_w  = (const float*)d_in[15];
    const float* out_b  = (const float*)d_in[16];
    const float* last_w = (const float*)d_in[17];
    const float* last_b = (const float*)d_in[18];
    float* out = (float*)d_out;

    float* ws      = (float*)d_ws;
    float* pooled1 = ws;                       // 64
    float* kern1   = ws + 64;                  // 576
    float* rowsum  = ws + 1024;                // 16384
    float* kern2   = ws + 17408;               // 1600
    _Float16* hwH   = (_Float16*)(ws + 19008); // 10368 fp16
    _Float16* owlwH = (_Float16*)(ws + 24192); // 8064 fp16 -> ends 28224
    float* y1      = ws + 32768;               // 4194304
    float* x1o     = ws + 32768 + 4194304;     // 4194304

    k_prep <<<8,    256, 0, stream>>>(hid_w, out_w, last_w, hwH, owlwH);
    k_pool <<<64,   256, 0, stream>>>(x, pooled1);
    k_kern1<<<1,    256, 0, stream>>>(pooled1, dl1_w1, dl1_b1, dl1_w2, dl1_b2, kern1);
    k_dw3  <<<2048, 256, 0, stream>>>(x, kern1, y1, rowsum);
    k_kern2<<<1,    256, 0, stream>>>(rowsum, dl2_w1, dl2_b1, dl2_w2, dl2_b2, kern2);
    k_dw5  <<<2048, 256, 0, stream>>>(y1, kern2, x1o);
    k_fsas <<<4096, 512, 0, stream>>>(x, hwH, hid_b, dw_w, dw_b, ln_w, ln_b,
                                      owlwH, out_b, last_b, x1o, out);
}